// Round 1
// baseline (1188.337 us; speedup 1.0000x reference)
//
#include <hip/hip_runtime.h>
#include <hip/hip_bf16.h>

#define NN 50000
#define DM 128
#define EE 800000
#define NH 4
#define HDIM 512      // NH * DM
#define NRELS 64
#define RDIM 64
#define LAYERS 2

typedef short frag8 __attribute__((ext_vector_type(8)));   // 8 bf16 (bits)
typedef float f32x4 __attribute__((ext_vector_type(4)));

__device__ __forceinline__ float b2f(unsigned short u) {
    unsigned v = ((unsigned)u) << 16;
    union { unsigned u; float f; } c; c.u = v; return c.f;
}
__device__ __forceinline__ unsigned short f2b(float f) {
    union { float f; unsigned u; } c; c.f = f;
    unsigned u = c.u;
    u += 0x7FFFu + ((u >> 16) & 1u);   // round-to-nearest-even
    return (unsigned short)(u >> 16);
}

// ---------------- CSR build ----------------
__global__ void count_kernel(const int* __restrict__ dst, int* __restrict__ counts) {
    int e = blockIdx.x * 256 + threadIdx.x;
    if (e < EE) atomicAdd(&counts[dst[e]], 1);
}

__global__ void scan_kernel(const int* __restrict__ counts, int* __restrict__ row_ptr, int n) {
    __shared__ int wsum[16];
    __shared__ int woff[17];
    int t = threadIdx.x;
    int lane = t & 63, wid = t >> 6;
    int carry = 0;
    if (t == 0) row_ptr[0] = 0;
    for (int base = 0; base < n; base += 1024) {
        int idx = base + t;
        int x = (idx < n) ? counts[idx] : 0;
        int incl = x;
        #pragma unroll
        for (int d = 1; d < 64; d <<= 1) {
            int y = __shfl_up(incl, d, 64);
            if (lane >= d) incl += y;
        }
        if (lane == 63) wsum[wid] = incl;
        __syncthreads();
        if (t == 0) {
            int s = 0;
            for (int w = 0; w < 16; ++w) { woff[w] = s; s += wsum[w]; }
            woff[16] = s;
        }
        __syncthreads();
        if (idx < n) row_ptr[idx + 1] = carry + woff[wid] + incl;
        carry += woff[16];
        __syncthreads();
    }
}

__global__ void cursor_init_kernel(const int* __restrict__ row_ptr, int* __restrict__ cursor) {
    int i = blockIdx.x * 256 + threadIdx.x;
    if (i < NN) cursor[i] = row_ptr[i];
}

__global__ void scatter_kernel(const int* __restrict__ dst, int* __restrict__ cursor,
                               int* __restrict__ perm) {
    int e = blockIdx.x * 256 + threadIdx.x;
    if (e < EE) {
        int p = atomicAdd(&cursor[dst[e]], 1);
        perm[p] = e;
    }
}

// ---------------- prep: W transpose->bf16, xe table ----------------
__global__ void wconv_kernel(const float* __restrict__ W, unsigned short* __restrict__ Wt) {
    int idx = blockIdx.x * 256 + threadIdx.x;
    if (idx >= DM * HDIM) return;
    int c = idx >> 7, k = idx & 127;            // Wt[c][k] = W[k][c]
    Wt[idx] = f2b(W[k * HDIM + c]);
}

__global__ void xe_kernel(const float* __restrict__ rel_emb,  // [64][64]
                          const float* __restrict__ We,        // [2][64][512]
                          float* __restrict__ xe) {            // [2][64][512]
    int idx = blockIdx.x * 256 + threadIdx.x;
    if (idx >= LAYERS * NRELS * HDIM) return;
    int l  = idx / (NRELS * HDIM);
    int r  = (idx / HDIM) & (NRELS - 1);
    int hc = idx & (HDIM - 1);
    const float* Wel = We + (size_t)l * RDIM * HDIM;
    float s = 0.f;
    #pragma unroll 8
    for (int d = 0; d < RDIM; ++d) s += rel_emb[r * RDIM + d] * Wel[d * HDIM + hc];
    xe[idx] = s;
}

// ---------------- GEMM: xl = h@Wl+bl, xr = h@Wr+br (bf16 out) ----------------
__global__ __launch_bounds__(256) void gemm_xlxr_kernel(
    const float* __restrict__ hmat,               // [NN,128]
    const unsigned short* __restrict__ WtL,       // [512][128] bf16 (transposed)
    const unsigned short* __restrict__ WtR,
    const float* __restrict__ bl, const float* __restrict__ br,
    unsigned short* __restrict__ xl, unsigned short* __restrict__ xr) {
    int w = threadIdx.x >> 6, lane = threadIdx.x & 63;
    int nbase = blockIdx.x * 128 + w * 32;
    int m0 = blockIdx.y * 16;
    int row_a = lane & 15, kg = lane >> 4;

    frag8 a[4];
    const float* arow = hmat + (size_t)(m0 + row_a) * DM;
    #pragma unroll
    for (int kc = 0; kc < 4; ++kc) {
        const float4* p = (const float4*)(arow + kc * 32 + kg * 8);
        float4 v0 = p[0], v1 = p[1];
        frag8 t;
        t[0] = (short)f2b(v0.x); t[1] = (short)f2b(v0.y);
        t[2] = (short)f2b(v0.z); t[3] = (short)f2b(v0.w);
        t[4] = (short)f2b(v1.x); t[5] = (short)f2b(v1.y);
        t[6] = (short)f2b(v1.z); t[7] = (short)f2b(v1.w);
        a[kc] = t;
    }
    int colL = lane & 15;
    #pragma unroll
    for (int mat = 0; mat < 2; ++mat) {
        const unsigned short* Wt = mat ? WtR : WtL;
        const float* bias = mat ? br : bl;
        unsigned short* out = mat ? xr : xl;
        #pragma unroll
        for (int nt = 0; nt < 2; ++nt) {
            int col = nbase + nt * 16 + colL;
            f32x4 acc = {0.f, 0.f, 0.f, 0.f};
            #pragma unroll
            for (int kc = 0; kc < 4; ++kc) {
                uint4 raw = *(const uint4*)(Wt + (size_t)col * DM + kc * 32 + kg * 8);
                frag8 b = __builtin_bit_cast(frag8, raw);
                acc = __builtin_amdgcn_mfma_f32_16x16x32_bf16(a[kc], b, acc, 0, 0, 0);
            }
            float bb = bias[col];
            #pragma unroll
            for (int r = 0; r < 4; ++r) {
                int row = m0 + kg * 4 + r;
                out[(size_t)row * HDIM + col] = f2b(acc[r] + bb);
            }
        }
    }
}

// ---------------- per-edge logits ----------------
__global__ __launch_bounds__(256) void edge_logits_kernel(
    const unsigned short* __restrict__ xl, const unsigned short* __restrict__ xr,
    const float* __restrict__ xe,          // [64][512] (this layer)
    const float* __restrict__ att,         // [4][128]  (this layer)
    const int* __restrict__ ei, const int* __restrict__ etype,
    float* __restrict__ logits) {
    int wid = threadIdx.x >> 6, lane = threadIdx.x & 63;
    int e = blockIdx.x * 4 + wid;
    if (e >= EE) return;
    int src = ei[e], dst = ei[EE + e], rel = etype[e];
    uint4 av = ((const uint4*)(xl + (size_t)src * HDIM))[lane];
    uint4 bv = ((const uint4*)(xr + (size_t)dst * HDIM))[lane];
    const float4* xer = (const float4*)(xe + rel * HDIM);
    float4 e0 = xer[2 * lane], e1 = xer[2 * lane + 1];
    const float4* attp = (const float4*)att;
    float4 t0 = attp[2 * lane], t1 = attp[2 * lane + 1];

    unsigned aw[4] = {av.x, av.y, av.z, av.w};
    unsigned bw[4] = {bv.x, bv.y, bv.z, bv.w};
    float ev[8] = {e0.x, e0.y, e0.z, e0.w, e1.x, e1.y, e1.z, e1.w};
    float tv[8] = {t0.x, t0.y, t0.z, t0.w, t1.x, t1.y, t1.z, t1.w};

    float partial = 0.f;
    #pragma unroll
    for (int j = 0; j < 4; ++j) {
        float x0 = b2f((unsigned short)aw[j]) + b2f((unsigned short)bw[j]) + ev[2 * j];
        float x1 = b2f((unsigned short)(aw[j] >> 16)) + b2f((unsigned short)(bw[j] >> 16)) + ev[2 * j + 1];
        x0 = x0 > 0.f ? x0 : 0.2f * x0;
        x1 = x1 > 0.f ? x1 : 0.2f * x1;
        partial += tv[2 * j] * x0 + tv[2 * j + 1] * x1;
    }
    #pragma unroll
    for (int d = 1; d < 16; d <<= 1) partial += __shfl_xor(partial, d, 64);
    if ((lane & 15) == 0) logits[(size_t)e * 4 + (lane >> 4)] = partial;
}

// ---------------- per-node: softmax + aggregate + mean + gelu + residual + LN ----------------
__device__ __forceinline__ float4 breduce4(float4 v, bool domax, float* red, int lane, int wid) {
    #pragma unroll
    for (int d = 1; d < 64; d <<= 1) {
        float ax = __shfl_xor(v.x, d, 64), ay = __shfl_xor(v.y, d, 64);
        float az = __shfl_xor(v.z, d, 64), aw = __shfl_xor(v.w, d, 64);
        if (domax) { v.x = fmaxf(v.x, ax); v.y = fmaxf(v.y, ay); v.z = fmaxf(v.z, az); v.w = fmaxf(v.w, aw); }
        else       { v.x += ax; v.y += ay; v.z += az; v.w += aw; }
    }
    if (lane == 0) { red[wid * 4 + 0] = v.x; red[wid * 4 + 1] = v.y; red[wid * 4 + 2] = v.z; red[wid * 4 + 3] = v.w; }
    __syncthreads();
    float4 r;
    if (domax) { r.x = fmaxf(red[0], red[4]); r.y = fmaxf(red[1], red[5]); r.z = fmaxf(red[2], red[6]); r.w = fmaxf(red[3], red[7]); }
    else       { r.x = red[0] + red[4]; r.y = red[1] + red[5]; r.z = red[2] + red[6]; r.w = red[3] + red[7]; }
    __syncthreads();
    return r;
}

__global__ __launch_bounds__(128) void node_fuse_kernel(
    const int* __restrict__ row_ptr, const int* __restrict__ perm,
    const int* __restrict__ ei,              // src = ei[e]
    const float* __restrict__ logits,        // [E][4]
    const unsigned short* __restrict__ xl,   // [NN][512] bf16
    const float* __restrict__ h_in,          // [NN][128]
    const float* __restrict__ b_out, const float* __restrict__ ln_g,
    const float* __restrict__ ln_b,
    float* __restrict__ h_out) {
    int i = blockIdx.x;
    int t = threadIdx.x;                 // 0..127
    int lane = t & 63, wid = t >> 6;
    __shared__ float red[8];
    __shared__ float alpha_l[128][4];
    __shared__ int   src_l[128];
    __shared__ float lsum[512];

    int beg = row_ptr[i], end = row_ptr[i + 1];
    float4 acc = {0.f, 0.f, 0.f, 0.f};

    float4 mxv = {-1e30f, -1e30f, -1e30f, -1e30f};
    for (int j = beg + t; j < end; j += 128) {
        float4 lg = ((const float4*)logits)[perm[j]];
        mxv.x = fmaxf(mxv.x, lg.x); mxv.y = fmaxf(mxv.y, lg.y);
        mxv.z = fmaxf(mxv.z, lg.z); mxv.w = fmaxf(mxv.w, lg.w);
    }
    float4 mx = breduce4(mxv, true, red, lane, wid);

    float4 sv = {0.f, 0.f, 0.f, 0.f};
    for (int j = beg + t; j < end; j += 128) {
        float4 lg = ((const float4*)logits)[perm[j]];
        sv.x += __expf(lg.x - mx.x); sv.y += __expf(lg.y - mx.y);
        sv.z += __expf(lg.z - mx.z); sv.w += __expf(lg.w - mx.w);
    }
    float4 den = breduce4(sv, false, red, lane, wid);
    float4 inv;
    inv.x = 1.f / den.x; inv.y = 1.f / den.y; inv.z = 1.f / den.z; inv.w = 1.f / den.w;

    int h = t >> 5;                       // head owned by this thread (4 contiguous channels)
    for (int cb = beg; cb < end; cb += 128) {
        int m = min(128, end - cb);
        if (t < m) {
            int p = perm[cb + t];
            float4 lg = ((const float4*)logits)[p];
            alpha_l[t][0] = __expf(lg.x - mx.x) * inv.x;
            alpha_l[t][1] = __expf(lg.y - mx.y) * inv.y;
            alpha_l[t][2] = __expf(lg.z - mx.z) * inv.z;
            alpha_l[t][3] = __expf(lg.w - mx.w) * inv.w;
            src_l[t] = ei[p];
        }
        __syncthreads();
        for (int j = 0; j < m; ++j) {
            int s = src_l[j];
            float a = alpha_l[j][h];
            ushort4 v = ((const ushort4*)(xl + (size_t)s * HDIM))[t];
            acc.x += a * b2f(v.x); acc.y += a * b2f(v.y);
            acc.z += a * b2f(v.z); acc.w += a * b2f(v.w);
        }
        __syncthreads();
    }

    lsum[4 * t + 0] = acc.x; lsum[4 * t + 1] = acc.y;
    lsum[4 * t + 2] = acc.z; lsum[4 * t + 3] = acc.w;
    __syncthreads();

    int c = t;
    float o = (lsum[c] + lsum[128 + c] + lsum[256 + c] + lsum[384 + c]) * 0.25f + b_out[c];
    float ge = 0.5f * o * (1.f + erff(o * 0.70710678118654752f));
    float y = h_in[(size_t)i * DM + c] + ge;

    float4 r = breduce4(make_float4(y, y * y, 0.f, 0.f), false, red, lane, wid);
    float mean = r.x * (1.f / 128.f);
    float var = r.y * (1.f / 128.f) - mean * mean;
    float rs = rsqrtf(var + 1e-5f);
    h_out[(size_t)i * DM + c] = (y - mean) * rs * ln_g[c] + ln_b[c];
}

// ---------------- launch ----------------
extern "C" void kernel_launch(void* const* d_in, const int* in_sizes, int n_in,
                              void* d_out, int out_size, void* d_ws, size_t ws_size,
                              hipStream_t stream) {
    const float* x_flat   = (const float*)d_in[0];
    const int*   edge_idx = (const int*)d_in[1];
    const int*   edge_ty  = (const int*)d_in[2];
    const float* rel_emb  = (const float*)d_in[3];
    const float* Wl       = (const float*)d_in[4];
    const float* bl       = (const float*)d_in[5];
    const float* Wr       = (const float*)d_in[6];
    const float* br       = (const float*)d_in[7];
    const float* We       = (const float*)d_in[8];
    const float* att      = (const float*)d_in[9];
    const float* b_out    = (const float*)d_in[10];
    const float* ln_g     = (const float*)d_in[11];
    const float* ln_b     = (const float*)d_in[12];

    char* p = (char*)d_ws;
    auto carve = [&](size_t bytes) {
        void* r = (void*)p;
        p += (bytes + 255) & ~(size_t)255;
        return r;
    };
    unsigned short* xl     = (unsigned short*)carve((size_t)NN * HDIM * 2);
    unsigned short* xr     = (unsigned short*)carve((size_t)NN * HDIM * 2);
    float*          logits = (float*)carve((size_t)EE * 4 * 4);
    float*          h1     = (float*)carve((size_t)NN * DM * 4);
    unsigned short* Wt     = (unsigned short*)carve((size_t)4 * DM * HDIM * 2);
    float*          xe     = (float*)carve((size_t)LAYERS * NRELS * HDIM * 4);
    int*            row_ptr= (int*)carve((size_t)(NN + 1) * 4);
    int*            counts = (int*)carve((size_t)NN * 4);
    int*            cursor = (int*)carve((size_t)NN * 4);
    int*            perm   = (int*)carve((size_t)EE * 4);

    const int* dst = edge_idx + EE;

    // CSR build
    hipMemsetAsync(counts, 0, (size_t)NN * 4, stream);
    count_kernel<<<(EE + 255) / 256, 256, 0, stream>>>(dst, counts);
    scan_kernel<<<1, 1024, 0, stream>>>(counts, row_ptr, NN);
    cursor_init_kernel<<<(NN + 255) / 256, 256, 0, stream>>>(row_ptr, cursor);
    scatter_kernel<<<(EE + 255) / 256, 256, 0, stream>>>(dst, cursor, perm);

    // weight prep
    for (int l = 0; l < LAYERS; ++l) {
        wconv_kernel<<<(DM * HDIM + 255) / 256, 256, 0, stream>>>(
            Wl + (size_t)l * DM * HDIM, Wt + (size_t)(l * 2 + 0) * DM * HDIM);
        wconv_kernel<<<(DM * HDIM + 255) / 256, 256, 0, stream>>>(
            Wr + (size_t)l * DM * HDIM, Wt + (size_t)(l * 2 + 1) * DM * HDIM);
    }
    xe_kernel<<<(LAYERS * NRELS * HDIM + 255) / 256, 256, 0, stream>>>(rel_emb, We, xe);

    const float* h_cur = x_flat;
    for (int l = 0; l < LAYERS; ++l) {
        float* h_next = (l == LAYERS - 1) ? (float*)d_out : h1;
        gemm_xlxr_kernel<<<dim3(4, NN / 16), 256, 0, stream>>>(
            h_cur,
            Wt + (size_t)(l * 2 + 0) * DM * HDIM,
            Wt + (size_t)(l * 2 + 1) * DM * HDIM,
            bl + (size_t)l * HDIM, br + (size_t)l * HDIM,
            xl, xr);
        edge_logits_kernel<<<EE / 4, 256, 0, stream>>>(
            xl, xr,
            xe + (size_t)l * NRELS * HDIM,
            att + (size_t)l * NH * DM,
            edge_idx, edge_ty, logits);
        node_fuse_kernel<<<NN, 128, 0, stream>>>(
            row_ptr, perm, edge_idx, logits, xl, h_cur,
            b_out + (size_t)l * DM, ln_g + (size_t)l * DM, ln_b + (size_t)l * DM,
            h_next);
        h_cur = h_next;
    }
}

// Round 2
// 825.053 us; speedup vs baseline: 1.4403x; 1.4403x over previous
//
#include <hip/hip_runtime.h>
#include <hip/hip_bf16.h>

#define NN 50000
#define DM 128
#define EE 800000
#define NH 4
#define HDIM 512      // NH * DM
#define NRELS 64
#define RDIM 64
#define LAYERS 2

typedef short frag8 __attribute__((ext_vector_type(8)));   // 8 bf16 (bits)
typedef float f32x4 __attribute__((ext_vector_type(4)));

__device__ __forceinline__ float b2f(unsigned short u) {
    unsigned v = ((unsigned)u) << 16;
    union { unsigned u; float f; } c; c.u = v; return c.f;
}
__device__ __forceinline__ unsigned short f2b(float f) {
    union { float f; unsigned u; } c; c.f = f;
    unsigned u = c.u;
    u += 0x7FFFu + ((u >> 16) & 1u);   // round-to-nearest-even
    return (unsigned short)(u >> 16);
}

// ---------------- CSR build ----------------
__global__ void count_kernel(const int* __restrict__ dst, int* __restrict__ counts) {
    int e = blockIdx.x * 256 + threadIdx.x;
    if (e < EE) atomicAdd(&counts[dst[e]], 1);
}

__global__ void scan_kernel(const int* __restrict__ counts, int* __restrict__ row_ptr, int n) {
    __shared__ int wsum[16];
    __shared__ int woff[17];
    int t = threadIdx.x;
    int lane = t & 63, wid = t >> 6;
    int carry = 0;
    if (t == 0) row_ptr[0] = 0;
    for (int base = 0; base < n; base += 1024) {
        int idx = base + t;
        int x = (idx < n) ? counts[idx] : 0;
        int incl = x;
        #pragma unroll
        for (int d = 1; d < 64; d <<= 1) {
            int y = __shfl_up(incl, d, 64);
            if (lane >= d) incl += y;
        }
        if (lane == 63) wsum[wid] = incl;
        __syncthreads();
        if (t == 0) {
            int s = 0;
            for (int w = 0; w < 16; ++w) { woff[w] = s; s += wsum[w]; }
            woff[16] = s;
        }
        __syncthreads();
        if (idx < n) row_ptr[idx + 1] = carry + woff[wid] + incl;
        carry += woff[16];
        __syncthreads();
    }
}

__global__ void cursor_init_kernel(const int* __restrict__ row_ptr, int* __restrict__ cursor) {
    int i = blockIdx.x * 256 + threadIdx.x;
    if (i < NN) cursor[i] = row_ptr[i];
}

__global__ void scatter_kernel(const int* __restrict__ dst, int* __restrict__ cursor,
                               int* __restrict__ perm) {
    int e = blockIdx.x * 256 + threadIdx.x;
    if (e < EE) {
        int p = atomicAdd(&cursor[dst[e]], 1);
        perm[p] = e;
    }
}

// ---------------- prep: W transpose->bf16, xe table (bf16) ----------------
__global__ void wconv_kernel(const float* __restrict__ W, unsigned short* __restrict__ Wt) {
    int idx = blockIdx.x * 256 + threadIdx.x;
    if (idx >= DM * HDIM) return;
    int c = idx >> 7, k = idx & 127;            // Wt[c][k] = W[k][c]
    Wt[idx] = f2b(W[k * HDIM + c]);
}

__global__ void xe_kernel(const float* __restrict__ rel_emb,  // [64][64]
                          const float* __restrict__ We,        // [2][64][512]
                          unsigned short* __restrict__ xeb) {  // [2][64][512] bf16
    int idx = blockIdx.x * 256 + threadIdx.x;
    if (idx >= LAYERS * NRELS * HDIM) return;
    int l  = idx / (NRELS * HDIM);
    int r  = (idx / HDIM) & (NRELS - 1);
    int hc = idx & (HDIM - 1);
    const float* Wel = We + (size_t)l * RDIM * HDIM;
    float s = 0.f;
    #pragma unroll 8
    for (int d = 0; d < RDIM; ++d) s += rel_emb[r * RDIM + d] * Wel[d * HDIM + hc];
    xeb[idx] = f2b(s);
}

// ---------------- GEMM: xl = h@Wl+bl, xr = h@Wr+br (bf16 out) ----------------
__global__ __launch_bounds__(256) void gemm_xlxr_kernel(
    const float* __restrict__ hmat,               // [NN,128]
    const unsigned short* __restrict__ WtL,       // [512][128] bf16 (transposed)
    const unsigned short* __restrict__ WtR,
    const float* __restrict__ bl, const float* __restrict__ br,
    unsigned short* __restrict__ xl, unsigned short* __restrict__ xr) {
    int w = threadIdx.x >> 6, lane = threadIdx.x & 63;
    int nbase = blockIdx.x * 128 + w * 32;
    int m0 = blockIdx.y * 16;
    int row_a = lane & 15, kg = lane >> 4;

    frag8 a[4];
    const float* arow = hmat + (size_t)(m0 + row_a) * DM;
    #pragma unroll
    for (int kc = 0; kc < 4; ++kc) {
        const float4* p = (const float4*)(arow + kc * 32 + kg * 8);
        float4 v0 = p[0], v1 = p[1];
        frag8 t;
        t[0] = (short)f2b(v0.x); t[1] = (short)f2b(v0.y);
        t[2] = (short)f2b(v0.z); t[3] = (short)f2b(v0.w);
        t[4] = (short)f2b(v1.x); t[5] = (short)f2b(v1.y);
        t[6] = (short)f2b(v1.z); t[7] = (short)f2b(v1.w);
        a[kc] = t;
    }
    int colL = lane & 15;
    #pragma unroll
    for (int mat = 0; mat < 2; ++mat) {
        const unsigned short* Wt = mat ? WtR : WtL;
        const float* bias = mat ? br : bl;
        unsigned short* out = mat ? xr : xl;
        #pragma unroll
        for (int nt = 0; nt < 2; ++nt) {
            int col = nbase + nt * 16 + colL;
            f32x4 acc = {0.f, 0.f, 0.f, 0.f};
            #pragma unroll
            for (int kc = 0; kc < 4; ++kc) {
                uint4 raw = *(const uint4*)(Wt + (size_t)col * DM + kc * 32 + kg * 8);
                frag8 b = __builtin_bit_cast(frag8, raw);
                acc = __builtin_amdgcn_mfma_f32_16x16x32_bf16(a[kc], b, acc, 0, 0, 0);
            }
            float bb = bias[col];
            #pragma unroll
            for (int r = 0; r < 4; ++r) {
                int row = m0 + kg * 4 + r;
                out[(size_t)row * HDIM + col] = f2b(acc[r] + bb);
            }
        }
    }
}

// ------- fused per-node: logits + online softmax + aggregate + mean + gelu + residual + LN -------
__device__ __forceinline__ float2 breduce2(float a, float b, float* red, int lane, int wid) {
    #pragma unroll
    for (int d = 1; d < 64; d <<= 1) {
        a += __shfl_xor(a, d, 64);
        b += __shfl_xor(b, d, 64);
    }
    if (lane == 0) { red[wid * 2 + 0] = a; red[wid * 2 + 1] = b; }
    __syncthreads();
    float2 r;
    r.x = red[0] + red[2];
    r.y = red[1] + red[3];
    __syncthreads();
    return r;
}

__global__ __launch_bounds__(128) void node_fused_kernel(
    const int* __restrict__ row_ptr, const int* __restrict__ perm,
    const int* __restrict__ ei,              // src = ei[e], dst = ei[EE+e]
    const int* __restrict__ etype,
    const unsigned short* __restrict__ xl,   // [NN][512] bf16
    const unsigned short* __restrict__ xr,   // [NN][512] bf16
    const unsigned short* __restrict__ xeb,  // [64][512] bf16 (this layer)
    const float* __restrict__ att,           // [512]     (this layer)
    const float* __restrict__ h_in,          // [NN][128]
    const float* __restrict__ b_out, const float* __restrict__ ln_g,
    const float* __restrict__ ln_b,
    float* __restrict__ h_out) {
    int i = blockIdx.x;
    int t = threadIdx.x;                 // 0..127, owns channels 4t..4t+3 of 512
    int lane = t & 63, wid = t >> 6;
    __shared__ int   src_l[128];
    __shared__ int   rel_l[128];
    __shared__ float lsum[512];
    __shared__ float red[4];

    int beg = row_ptr[i], end = row_ptr[i + 1];

    ushort4 xrv = ((const ushort4*)(xr + (size_t)i * HDIM))[t];
    float xr0 = b2f(xrv.x), xr1 = b2f(xrv.y), xr2 = b2f(xrv.z), xr3 = b2f(xrv.w);
    float4 at = ((const float4*)att)[t];

    float m = -1e30f, ssum = 0.f;
    f32x4 acc = {0.f, 0.f, 0.f, 0.f};

    for (int cb = beg; cb < end; cb += 128) {
        int mc = min(128, end - cb);
        if (t < mc) {
            int p = perm[cb + t];
            src_l[t] = ei[p];
            rel_l[t] = etype[p];
        }
        __syncthreads();
        for (int j = 0; j < mc; ++j) {
            int sidx = src_l[j], r = rel_l[j];
            ushort4 v  = ((const ushort4*)(xl  + (size_t)sidx * HDIM))[t];
            ushort4 ev = ((const ushort4*)(xeb + (size_t)r    * HDIM))[t];
            float x0 = b2f(v.x), x1 = b2f(v.y), x2 = b2f(v.z), x3 = b2f(v.w);
            float s0 = x0 + xr0 + b2f(ev.x);
            float s1 = x1 + xr1 + b2f(ev.y);
            float s2 = x2 + xr2 + b2f(ev.z);
            float s3 = x3 + xr3 + b2f(ev.w);
            s0 = s0 > 0.f ? s0 : 0.2f * s0;
            s1 = s1 > 0.f ? s1 : 0.2f * s1;
            s2 = s2 > 0.f ? s2 : 0.2f * s2;
            s3 = s3 > 0.f ? s3 : 0.2f * s3;
            float partial = at.x * s0 + at.y * s1 + at.z * s2 + at.w * s3;
            // per-head logit: reduce over the 32-lane group owning this head
            #pragma unroll
            for (int d = 1; d < 32; d <<= 1) partial += __shfl_xor(partial, d, 64);
            // online softmax update (exact)
            float mn = fmaxf(m, partial);
            float sc = __expf(m - mn);
            float w  = __expf(partial - mn);
            ssum = ssum * sc + w;
            acc[0] = acc[0] * sc + w * x0;
            acc[1] = acc[1] * sc + w * x1;
            acc[2] = acc[2] * sc + w * x2;
            acc[3] = acc[3] * sc + w * x3;
            m = mn;
        }
        __syncthreads();
    }

    float invs = (ssum > 0.f) ? 1.f / ssum : 0.f;
    lsum[4 * t + 0] = acc[0] * invs;
    lsum[4 * t + 1] = acc[1] * invs;
    lsum[4 * t + 2] = acc[2] * invs;
    lsum[4 * t + 3] = acc[3] * invs;
    __syncthreads();

    int c = t;
    float o = (lsum[c] + lsum[128 + c] + lsum[256 + c] + lsum[384 + c]) * 0.25f + b_out[c];
    float ge = 0.5f * o * (1.f + erff(o * 0.70710678118654752f));
    float y = h_in[(size_t)i * DM + c] + ge;

    float2 r = breduce2(y, y * y, red, lane, wid);
    float mean = r.x * (1.f / 128.f);
    float var = r.y * (1.f / 128.f) - mean * mean;
    float rs = rsqrtf(var + 1e-5f);
    h_out[(size_t)i * DM + c] = (y - mean) * rs * ln_g[c] + ln_b[c];
}

// ---------------- launch ----------------
extern "C" void kernel_launch(void* const* d_in, const int* in_sizes, int n_in,
                              void* d_out, int out_size, void* d_ws, size_t ws_size,
                              hipStream_t stream) {
    const float* x_flat   = (const float*)d_in[0];
    const int*   edge_idx = (const int*)d_in[1];
    const int*   edge_ty  = (const int*)d_in[2];
    const float* rel_emb  = (const float*)d_in[3];
    const float* Wl       = (const float*)d_in[4];
    const float* bl       = (const float*)d_in[5];
    const float* Wr       = (const float*)d_in[6];
    const float* br       = (const float*)d_in[7];
    const float* We       = (const float*)d_in[8];
    const float* att      = (const float*)d_in[9];
    const float* b_out    = (const float*)d_in[10];
    const float* ln_g     = (const float*)d_in[11];
    const float* ln_b     = (const float*)d_in[12];

    char* p = (char*)d_ws;
    auto carve = [&](size_t bytes) {
        void* r = (void*)p;
        p += (bytes + 255) & ~(size_t)255;
        return r;
    };
    unsigned short* xl     = (unsigned short*)carve((size_t)NN * HDIM * 2);
    unsigned short* xr     = (unsigned short*)carve((size_t)NN * HDIM * 2);
    float*          h1     = (float*)carve((size_t)NN * DM * 4);
    unsigned short* Wt     = (unsigned short*)carve((size_t)4 * DM * HDIM * 2);
    unsigned short* xeb    = (unsigned short*)carve((size_t)LAYERS * NRELS * HDIM * 2);
    int*            row_ptr= (int*)carve((size_t)(NN + 1) * 4);
    int*            counts = (int*)carve((size_t)NN * 4);
    int*            cursor = (int*)carve((size_t)NN * 4);
    int*            perm   = (int*)carve((size_t)EE * 4);

    const int* dst = edge_idx + EE;

    // CSR build
    hipMemsetAsync(counts, 0, (size_t)NN * 4, stream);
    count_kernel<<<(EE + 255) / 256, 256, 0, stream>>>(dst, counts);
    scan_kernel<<<1, 1024, 0, stream>>>(counts, row_ptr, NN);
    cursor_init_kernel<<<(NN + 255) / 256, 256, 0, stream>>>(row_ptr, cursor);
    scatter_kernel<<<(EE + 255) / 256, 256, 0, stream>>>(dst, cursor, perm);

    // weight prep
    for (int l = 0; l < LAYERS; ++l) {
        wconv_kernel<<<(DM * HDIM + 255) / 256, 256, 0, stream>>>(
            Wl + (size_t)l * DM * HDIM, Wt + (size_t)(l * 2 + 0) * DM * HDIM);
        wconv_kernel<<<(DM * HDIM + 255) / 256, 256, 0, stream>>>(
            Wr + (size_t)l * DM * HDIM, Wt + (size_t)(l * 2 + 1) * DM * HDIM);
    }
    xe_kernel<<<(LAYERS * NRELS * HDIM + 255) / 256, 256, 0, stream>>>(rel_emb, We, xeb);

    const float* h_cur = x_flat;
    for (int l = 0; l < LAYERS; ++l) {
        float* h_next = (l == LAYERS - 1) ? (float*)d_out : h1;
        gemm_xlxr_kernel<<<dim3(4, NN / 16), 256, 0, stream>>>(
            h_cur,
            Wt + (size_t)(l * 2 + 0) * DM * HDIM,
            Wt + (size_t)(l * 2 + 1) * DM * HDIM,
            bl + (size_t)l * HDIM, br + (size_t)l * HDIM,
            xl, xr);
        node_fused_kernel<<<NN, 128, 0, stream>>>(
            row_ptr, perm, edge_idx, edge_ty, xl, xr,
            xeb + (size_t)l * NRELS * HDIM,
            att + (size_t)l * NH * DM,
            h_cur,
            b_out + (size_t)l * DM, ln_g + (size_t)l * DM, ln_b + (size_t)l * DM,
            h_next);
        h_cur = h_next;
    }
}

// Round 3
// 801.165 us; speedup vs baseline: 1.4833x; 1.0298x over previous
//
#include <hip/hip_runtime.h>
#include <hip/hip_bf16.h>

#define NN 50000
#define DM 128
#define EE 800000
#define NH 4
#define HDIM 512      // NH * DM
#define NRELS 64
#define RDIM 64
#define LAYERS 2

typedef short frag8 __attribute__((ext_vector_type(8)));   // 8 bf16 (bits)
typedef float f32x4 __attribute__((ext_vector_type(4)));

__device__ __forceinline__ float b2f(unsigned short u) {
    unsigned v = ((unsigned)u) << 16;
    union { unsigned u; float f; } c; c.u = v; return c.f;
}
__device__ __forceinline__ float b2f_lo(unsigned u) {
    union { unsigned u; float f; } c; c.u = u << 16; return c.f;
}
__device__ __forceinline__ float b2f_hi(unsigned u) {
    union { unsigned u; float f; } c; c.u = u & 0xFFFF0000u; return c.f;
}
__device__ __forceinline__ unsigned short f2b(float f) {
    union { float f; unsigned u; } c; c.f = f;
    unsigned u = c.u;
    u += 0x7FFFu + ((u >> 16) & 1u);   // round-to-nearest-even
    return (unsigned short)(u >> 16);
}

// ---------------- CSR build ----------------
__global__ void count_kernel(const int* __restrict__ dst, int* __restrict__ counts) {
    int e = blockIdx.x * 256 + threadIdx.x;
    if (e < EE) atomicAdd(&counts[dst[e]], 1);
}

__global__ void scan_kernel(const int* __restrict__ counts, int* __restrict__ row_ptr, int n) {
    __shared__ int wsum[16];
    __shared__ int woff[17];
    int t = threadIdx.x;
    int lane = t & 63, wid = t >> 6;
    int carry = 0;
    if (t == 0) row_ptr[0] = 0;
    for (int base = 0; base < n; base += 1024) {
        int idx = base + t;
        int x = (idx < n) ? counts[idx] : 0;
        int incl = x;
        #pragma unroll
        for (int d = 1; d < 64; d <<= 1) {
            int y = __shfl_up(incl, d, 64);
            if (lane >= d) incl += y;
        }
        if (lane == 63) wsum[wid] = incl;
        __syncthreads();
        if (t == 0) {
            int s = 0;
            for (int w = 0; w < 16; ++w) { woff[w] = s; s += wsum[w]; }
            woff[16] = s;
        }
        __syncthreads();
        if (idx < n) row_ptr[idx + 1] = carry + woff[wid] + incl;
        carry += woff[16];
        __syncthreads();
    }
}

__global__ void cursor_init_kernel(const int* __restrict__ row_ptr, int* __restrict__ cursor) {
    int i = blockIdx.x * 256 + threadIdx.x;
    if (i < NN) cursor[i] = row_ptr[i];
}

__global__ void scatter_kernel(const int* __restrict__ dst, int* __restrict__ cursor,
                               int* __restrict__ perm) {
    int e = blockIdx.x * 256 + threadIdx.x;
    if (e < EE) {
        int p = atomicAdd(&cursor[dst[e]], 1);
        perm[p] = e;
    }
}

// ---------------- prep kernels ----------------
__global__ void wconv_kernel(const float* __restrict__ W, unsigned short* __restrict__ Wt) {
    int idx = blockIdx.x * 256 + threadIdx.x;
    if (idx >= DM * HDIM) return;
    int c = idx >> 7, k = idx & 127;            // Wt[c][k] = W[k][c]
    Wt[idx] = f2b(W[k * HDIM + c]);
}

__global__ void hb_kernel(const float* __restrict__ h, unsigned short* __restrict__ hb, int n4) {
    int idx = blockIdx.x * 256 + threadIdx.x;
    if (idx >= n4) return;
    float4 v = ((const float4*)h)[idx];
    ushort4 o;
    o.x = f2b(v.x); o.y = f2b(v.y); o.z = f2b(v.z); o.w = f2b(v.w);
    ((ushort4*)hb)[idx] = o;
}

__global__ void xe_kernel(const float* __restrict__ rel_emb,  // [64][64]
                          const float* __restrict__ We,        // [2][64][512]
                          float* __restrict__ xef) {           // [2][64][512] f32
    int idx = blockIdx.x * 256 + threadIdx.x;
    if (idx >= LAYERS * NRELS * HDIM) return;
    int l  = idx / (NRELS * HDIM);
    int r  = (idx / HDIM) & (NRELS - 1);
    int hc = idx & (HDIM - 1);
    const float* Wel = We + (size_t)l * RDIM * HDIM;
    float s = 0.f;
    #pragma unroll 8
    for (int d = 0; d < RDIM; ++d) s += rel_emb[r * RDIM + d] * Wel[d * HDIM + hc];
    xef[idx] = s;
}

// be[l][r][h] = 0.6 * sum_c att[l][h][c] * xe[l][r][h*128+c]
__global__ void be_kernel(const float* __restrict__ xef, const float* __restrict__ att,
                          float* __restrict__ be) {
    int tid = blockIdx.x * 256 + threadIdx.x;
    if (tid >= LAYERS * NRELS * NH) return;
    int l = tid >> 8;
    int r = (tid >> 2) & 63;
    int hh = tid & 3;
    const float* xp = xef + (size_t)l * NRELS * HDIM + r * HDIM + hh * DM;
    const float* ap = att + (size_t)l * HDIM + hh * DM;
    float s = 0.f;
    #pragma unroll 8
    for (int c = 0; c < DM; ++c) s += ap[c] * xp[c];
    be[tid] = 0.6f * s;
}

// ab[n][h]   = 0.6 * att_h . xl[n]   (h in 0..3)
// ab[n][4+h] = 0.6 * att_h . xr[n]
__global__ __launch_bounds__(256) void ab_kernel(
    const unsigned short* __restrict__ xl, const unsigned short* __restrict__ xr,
    const float* __restrict__ att_l, float* __restrict__ ab) {
    int wid = threadIdx.x >> 6, lane = threadIdx.x & 63;
    int n = blockIdx.x * 4 + wid;
    int head = lane >> 4;
    const float4* ap = (const float4*)(att_l + lane * 8);
    float4 a0 = ap[0], a1 = ap[1];
    uint4 lv = *(const uint4*)(xl + (size_t)n * HDIM + lane * 8);
    uint4 rv = *(const uint4*)(xr + (size_t)n * HDIM + lane * 8);
    float pl = 0.f, pr = 0.f;
    unsigned lw[4] = {lv.x, lv.y, lv.z, lv.w};
    unsigned rw[4] = {rv.x, rv.y, rv.z, rv.w};
    float av[8] = {a0.x, a0.y, a0.z, a0.w, a1.x, a1.y, a1.z, a1.w};
    #pragma unroll
    for (int j = 0; j < 4; ++j) {
        pl = fmaf(av[2 * j],     b2f_lo(lw[j]), pl);
        pl = fmaf(av[2 * j + 1], b2f_hi(lw[j]), pl);
        pr = fmaf(av[2 * j],     b2f_lo(rw[j]), pr);
        pr = fmaf(av[2 * j + 1], b2f_hi(rw[j]), pr);
    }
    #pragma unroll
    for (int d = 1; d < 16; d <<= 1) {
        pl += __shfl_xor(pl, d, 64);
        pr += __shfl_xor(pr, d, 64);
    }
    if ((lane & 15) == 0) {
        ab[(size_t)n * 8 + head]     = 0.6f * pl;
        ab[(size_t)n * 8 + 4 + head] = 0.6f * pr;
    }
}

// ---------------- GEMM: xl = h@Wl+bl, xr = h@Wr+br (bf16 A input) ----------------
__global__ __launch_bounds__(256) void gemm_xlxr_kernel(
    const unsigned short* __restrict__ hb,        // [NN,128] bf16
    const unsigned short* __restrict__ WtL,       // [512][128] bf16 (transposed)
    const unsigned short* __restrict__ WtR,
    const float* __restrict__ bl, const float* __restrict__ br,
    unsigned short* __restrict__ xl, unsigned short* __restrict__ xr) {
    int w = threadIdx.x >> 6, lane = threadIdx.x & 63;
    int nbase = blockIdx.x * 128 + w * 32;
    int m0 = blockIdx.y * 16;
    int row_a = lane & 15, kg = lane >> 4;

    frag8 a[4];
    const unsigned short* arow = hb + (size_t)(m0 + row_a) * DM;
    #pragma unroll
    for (int kc = 0; kc < 4; ++kc) {
        uint4 raw = *(const uint4*)(arow + kc * 32 + kg * 8);
        a[kc] = __builtin_bit_cast(frag8, raw);
    }
    int colL = lane & 15;
    #pragma unroll
    for (int mat = 0; mat < 2; ++mat) {
        const unsigned short* Wt = mat ? WtR : WtL;
        const float* bias = mat ? br : bl;
        unsigned short* out = mat ? xr : xl;
        #pragma unroll
        for (int nt = 0; nt < 2; ++nt) {
            int col = nbase + nt * 16 + colL;
            f32x4 acc = {0.f, 0.f, 0.f, 0.f};
            #pragma unroll
            for (int kc = 0; kc < 4; ++kc) {
                uint4 raw = *(const uint4*)(Wt + (size_t)col * DM + kc * 32 + kg * 8);
                frag8 b = __builtin_bit_cast(frag8, raw);
                acc = __builtin_amdgcn_mfma_f32_16x16x32_bf16(a[kc], b, acc, 0, 0, 0);
            }
            float bb = bias[col];
            #pragma unroll
            for (int r = 0; r < 4; ++r) {
                int row = m0 + kg * 4 + r;
                out[(size_t)row * HDIM + col] = f2b(acc[r] + bb);
            }
        }
    }
}

// ------- fused per-node: logits + softmax + aggregate + mean + gelu + residual + LN -------
__device__ __forceinline__ float2 breduce2(float a, float b, float* red, int lane, int wid) {
    #pragma unroll
    for (int d = 1; d < 64; d <<= 1) {
        a += __shfl_xor(a, d, 64);
        b += __shfl_xor(b, d, 64);
    }
    if (lane == 0) { red[wid * 2 + 0] = a; red[wid * 2 + 1] = b; }
    __syncthreads();
    float2 r;
    r.x = red[0] + red[2];
    r.y = red[1] + red[3];
    __syncthreads();
    return r;
}

__global__ __launch_bounds__(128) void node_fused_kernel(
    const int* __restrict__ row_ptr, const int* __restrict__ perm,
    const int* __restrict__ ei,              // src = ei[e]
    const int* __restrict__ etype,
    const unsigned short* __restrict__ xl,   // [NN][512] bf16
    const unsigned short* __restrict__ xr,   // [NN][512] bf16
    const float* __restrict__ xef_l,         // [64][512] f32 (this layer)
    const float* __restrict__ ab,            // [NN][8] f32
    const float* __restrict__ be_l,          // [64][4] f32 (this layer)
    const float* __restrict__ att_l,         // [512] (this layer)
    const float* __restrict__ h_in,          // [NN][128]
    const float* __restrict__ b_out, const float* __restrict__ ln_g,
    const float* __restrict__ ln_b,
    float* __restrict__ h_out,
    unsigned short* __restrict__ hb_out) {   // bf16 copy for next layer's GEMM
    int i = blockIdx.x;
    int t = threadIdx.x;                 // 0..127, owns channels 4t..4t+3 of 512
    int lane = t & 63, wid = t >> 6;
    int hh = t >> 5;                     // head
    __shared__ uint2 ox_l[128];          // {src*1024, rel*2048} byte offsets
    __shared__ float cl[128][4];         // per-edge linear term per head
    __shared__ float lsum[512];
    __shared__ float red[4];

    int beg = row_ptr[i], end = row_ptr[i + 1];

    ushort4 xrv = ((const ushort4*)(xr + (size_t)i * HDIM))[t];
    float xr0 = b2f(xrv.x), xr1 = b2f(xrv.y), xr2 = b2f(xrv.z), xr3 = b2f(xrv.w);
    float4 at = ((const float4*)att_l)[t];
    at.x *= 0.4f; at.y *= 0.4f; at.z *= 0.4f; at.w *= 0.4f;
    float4 bxv = ((const float4*)ab)[2 * i + 1];   // 0.6 att.xr_i  (per head)

    const char* xl_b = (const char*)xl;
    const char* xe_b = (const char*)xef_l;
    const float* clp = &cl[0][0];
    uint t8 = (uint)t << 3, t16 = (uint)t << 4;

    float ssum = 0.f;
    float acc0 = 0.f, acc1 = 0.f, acc2 = 0.f, acc3 = 0.f;

    for (int cb = beg; cb < end; cb += 128) {
        int mc = min(128, end - cb);
        if (t < mc) {
            int p = perm[cb + t];
            int s = ei[p];
            int r = etype[p];
            ox_l[t].x = (uint)s << 10;
            ox_l[t].y = (uint)r << 11;
            float4 a4  = ((const float4*)ab)[2 * s];
            float4 be4 = ((const float4*)be_l)[r];
            cl[t][0] = a4.x + bxv.x + be4.x;
            cl[t][1] = a4.y + bxv.y + be4.y;
            cl[t][2] = a4.z + bxv.z + be4.z;
            cl[t][3] = a4.w + bxv.w + be4.w;
        }
        __syncthreads();
        for (int j = 0; j < mc; ++j) {
            uint2 oo = ox_l[j];
            float cj = clp[j * 4 + hh];
            uint2 vv = *(const uint2*)(xl_b + oo.x + t8);
            float4 ee = *(const float4*)(xe_b + oo.y + t16);
            float x0 = b2f_lo(vv.x), x1 = b2f_hi(vv.x);
            float x2 = b2f_lo(vv.y), x3 = b2f_hi(vv.y);
            float z0 = (x0 + xr0) + ee.x;
            float z1 = (x1 + xr1) + ee.y;
            float z2 = (x2 + xr2) + ee.z;
            float z3 = (x3 + xr3) + ee.w;
            float partial = fmaf(at.x, fabsf(z0),
                            fmaf(at.y, fabsf(z1),
                            fmaf(at.z, fabsf(z2), at.w * fabsf(z3))));
            #pragma unroll
            for (int d = 1; d < 32; d <<= 1) partial += __shfl_xor(partial, d, 64);
            float w = __expf(partial + cj);
            ssum += w;
            acc0 = fmaf(w, x0, acc0);
            acc1 = fmaf(w, x1, acc1);
            acc2 = fmaf(w, x2, acc2);
            acc3 = fmaf(w, x3, acc3);
        }
        __syncthreads();
    }

    float invs = (ssum > 0.f) ? 1.f / ssum : 0.f;
    lsum[4 * t + 0] = acc0 * invs;
    lsum[4 * t + 1] = acc1 * invs;
    lsum[4 * t + 2] = acc2 * invs;
    lsum[4 * t + 3] = acc3 * invs;
    __syncthreads();

    int c = t;
    float o = (lsum[c] + lsum[128 + c] + lsum[256 + c] + lsum[384 + c]) * 0.25f + b_out[c];
    float ge = 0.5f * o * (1.f + erff(o * 0.70710678118654752f));
    float y = h_in[(size_t)i * DM + c] + ge;

    float2 r = breduce2(y, y * y, red, lane, wid);
    float mean = r.x * (1.f / 128.f);
    float var = r.y * (1.f / 128.f) - mean * mean;
    float rs = rsqrtf(var + 1e-5f);
    float out = (y - mean) * rs * ln_g[c] + ln_b[c];
    h_out[(size_t)i * DM + c] = out;
    hb_out[(size_t)i * DM + c] = f2b(out);
}

// ---------------- launch ----------------
extern "C" void kernel_launch(void* const* d_in, const int* in_sizes, int n_in,
                              void* d_out, int out_size, void* d_ws, size_t ws_size,
                              hipStream_t stream) {
    const float* x_flat   = (const float*)d_in[0];
    const int*   edge_idx = (const int*)d_in[1];
    const int*   edge_ty  = (const int*)d_in[2];
    const float* rel_emb  = (const float*)d_in[3];
    const float* Wl       = (const float*)d_in[4];
    const float* bl       = (const float*)d_in[5];
    const float* Wr       = (const float*)d_in[6];
    const float* br       = (const float*)d_in[7];
    const float* We       = (const float*)d_in[8];
    const float* att      = (const float*)d_in[9];
    const float* b_out    = (const float*)d_in[10];
    const float* ln_g     = (const float*)d_in[11];
    const float* ln_b     = (const float*)d_in[12];

    char* p = (char*)d_ws;
    auto carve = [&](size_t bytes) {
        void* r = (void*)p;
        p += (bytes + 255) & ~(size_t)255;
        return r;
    };
    unsigned short* xl     = (unsigned short*)carve((size_t)NN * HDIM * 2);
    unsigned short* xr     = (unsigned short*)carve((size_t)NN * HDIM * 2);
    float*          h1     = (float*)carve((size_t)NN * DM * 4);
    unsigned short* hb     = (unsigned short*)carve((size_t)NN * DM * 2);
    unsigned short* Wt     = (unsigned short*)carve((size_t)4 * DM * HDIM * 2);
    float*          xef    = (float*)carve((size_t)LAYERS * NRELS * HDIM * 4);
    float*          ab     = (float*)carve((size_t)NN * 8 * 4);
    float*          be     = (float*)carve((size_t)LAYERS * NRELS * NH * 4);
    int*            row_ptr= (int*)carve((size_t)(NN + 1) * 4);
    int*            counts = (int*)carve((size_t)NN * 4);
    int*            cursor = (int*)carve((size_t)NN * 4);
    int*            perm   = (int*)carve((size_t)EE * 4);

    const int* dst = edge_idx + EE;

    // CSR build
    hipMemsetAsync(counts, 0, (size_t)NN * 4, stream);
    count_kernel<<<(EE + 255) / 256, 256, 0, stream>>>(dst, counts);
    scan_kernel<<<1, 1024, 0, stream>>>(counts, row_ptr, NN);
    cursor_init_kernel<<<(NN + 255) / 256, 256, 0, stream>>>(row_ptr, cursor);
    scatter_kernel<<<(EE + 255) / 256, 256, 0, stream>>>(dst, cursor, perm);

    // weight prep
    for (int l = 0; l < LAYERS; ++l) {
        wconv_kernel<<<(DM * HDIM + 255) / 256, 256, 0, stream>>>(
            Wl + (size_t)l * DM * HDIM, Wt + (size_t)(l * 2 + 0) * DM * HDIM);
        wconv_kernel<<<(DM * HDIM + 255) / 256, 256, 0, stream>>>(
            Wr + (size_t)l * DM * HDIM, Wt + (size_t)(l * 2 + 1) * DM * HDIM);
    }
    xe_kernel<<<(LAYERS * NRELS * HDIM + 255) / 256, 256, 0, stream>>>(rel_emb, We, xef);
    be_kernel<<<(LAYERS * NRELS * NH + 255) / 256, 256, 0, stream>>>(xef, att, be);
    hb_kernel<<<(NN * DM / 4 + 255) / 256, 256, 0, stream>>>(x_flat, hb, NN * DM / 4);

    const float* h_cur = x_flat;
    for (int l = 0; l < LAYERS; ++l) {
        float* h_next = (l == LAYERS - 1) ? (float*)d_out : h1;
        gemm_xlxr_kernel<<<dim3(4, NN / 16), 256, 0, stream>>>(
            hb,
            Wt + (size_t)(l * 2 + 0) * DM * HDIM,
            Wt + (size_t)(l * 2 + 1) * DM * HDIM,
            bl + (size_t)l * HDIM, br + (size_t)l * HDIM,
            xl, xr);
        ab_kernel<<<NN / 4, 256, 0, stream>>>(xl, xr, att + (size_t)l * HDIM, ab);
        node_fused_kernel<<<NN, 128, 0, stream>>>(
            row_ptr, perm, edge_idx, edge_ty, xl, xr,
            xef + (size_t)l * NRELS * HDIM,
            ab, be + (size_t)l * NRELS * NH,
            att + (size_t)l * HDIM,
            h_cur,
            b_out + (size_t)l * DM, ln_g + (size_t)l * DM, ln_b + (size_t)l * DM,
            h_next, hb);
        h_cur = h_next;
    }
}

// Round 4
// 764.436 us; speedup vs baseline: 1.5545x; 1.0480x over previous
//
#include <hip/hip_runtime.h>
#include <hip/hip_bf16.h>

#define NN 50000
#define DM 128
#define EE 800000
#define NH 4
#define HDIM 512      // NH * DM
#define NRELS 64
#define RDIM 64
#define LAYERS 2

typedef short frag8 __attribute__((ext_vector_type(8)));   // 8 bf16 (bits)
typedef float f32x4 __attribute__((ext_vector_type(4)));

__device__ __forceinline__ float b2f(unsigned short u) {
    unsigned v = ((unsigned)u) << 16;
    union { unsigned u; float f; } c; c.u = v; return c.f;
}
__device__ __forceinline__ float b2f_lo(unsigned u) {
    union { unsigned u; float f; } c; c.u = u << 16; return c.f;
}
__device__ __forceinline__ float b2f_hi(unsigned u) {
    union { unsigned u; float f; } c; c.u = u & 0xFFFF0000u; return c.f;
}
__device__ __forceinline__ unsigned short f2b(float f) {
    union { float f; unsigned u; } c; c.f = f;
    unsigned u = c.u;
    u += 0x7FFFu + ((u >> 16) & 1u);   // round-to-nearest-even
    return (unsigned short)(u >> 16);
}

// ---------------- CSR build ----------------
__global__ void count_kernel(const int* __restrict__ dst, int* __restrict__ counts) {
    int e = blockIdx.x * 256 + threadIdx.x;
    if (e < EE) atomicAdd(&counts[dst[e]], 1);
}

__global__ void scan_kernel(const int* __restrict__ counts, int* __restrict__ row_ptr, int n) {
    __shared__ int wsum[16];
    __shared__ int woff[17];
    int t = threadIdx.x;
    int lane = t & 63, wid = t >> 6;
    int carry = 0;
    if (t == 0) row_ptr[0] = 0;
    for (int base = 0; base < n; base += 1024) {
        int idx = base + t;
        int x = (idx < n) ? counts[idx] : 0;
        int incl = x;
        #pragma unroll
        for (int d = 1; d < 64; d <<= 1) {
            int y = __shfl_up(incl, d, 64);
            if (lane >= d) incl += y;
        }
        if (lane == 63) wsum[wid] = incl;
        __syncthreads();
        if (t == 0) {
            int s = 0;
            for (int w = 0; w < 16; ++w) { woff[w] = s; s += wsum[w]; }
            woff[16] = s;
        }
        __syncthreads();
        if (idx < n) row_ptr[idx + 1] = carry + woff[wid] + incl;
        carry += woff[16];
        __syncthreads();
    }
}

__global__ void cursor_init_kernel(const int* __restrict__ row_ptr, int* __restrict__ cursor) {
    int i = blockIdx.x * 256 + threadIdx.x;
    if (i < NN) cursor[i] = row_ptr[i];
}

__global__ void scatter_kernel(const int* __restrict__ dst, int* __restrict__ cursor,
                               int* __restrict__ perm) {
    int e = blockIdx.x * 256 + threadIdx.x;
    if (e < EE) {
        int p = atomicAdd(&cursor[dst[e]], 1);
        perm[p] = e;
    }
}

// ---------------- prep kernels ----------------
__global__ void wconv_kernel(const float* __restrict__ W, unsigned short* __restrict__ Wt) {
    int idx = blockIdx.x * 256 + threadIdx.x;
    if (idx >= DM * HDIM) return;
    int c = idx >> 7, k = idx & 127;            // Wt[c][k] = W[k][c]
    Wt[idx] = f2b(W[k * HDIM + c]);
}

__global__ void hb_kernel(const float* __restrict__ h, unsigned short* __restrict__ hb, int n4) {
    int idx = blockIdx.x * 256 + threadIdx.x;
    if (idx >= n4) return;
    float4 v = ((const float4*)h)[idx];
    ushort4 o;
    o.x = f2b(v.x); o.y = f2b(v.y); o.z = f2b(v.z); o.w = f2b(v.w);
    ((ushort4*)hb)[idx] = o;
}

__global__ void xe_kernel(const float* __restrict__ rel_emb,  // [64][64]
                          const float* __restrict__ We,        // [2][64][512]
                          unsigned short* __restrict__ xeb) {  // [2][64][512] bf16
    int idx = blockIdx.x * 256 + threadIdx.x;
    if (idx >= LAYERS * NRELS * HDIM) return;
    int l  = idx / (NRELS * HDIM);
    int r  = (idx / HDIM) & (NRELS - 1);
    int hc = idx & (HDIM - 1);
    const float* Wel = We + (size_t)l * RDIM * HDIM;
    float s = 0.f;
    #pragma unroll 8
    for (int d = 0; d < RDIM; ++d) s += rel_emb[r * RDIM + d] * Wel[d * HDIM + hc];
    xeb[idx] = f2b(s);
}

// be[l][r][h] = 0.6 * sum_c att[l][h][c] * xe[l][r][h*128+c]  (from bf16 table, consistent)
__global__ void be_kernel(const unsigned short* __restrict__ xeb, const float* __restrict__ att,
                          float* __restrict__ be) {
    int tid = blockIdx.x * 256 + threadIdx.x;
    if (tid >= LAYERS * NRELS * NH) return;
    int l = tid >> 8;
    int r = (tid >> 2) & 63;
    int hh = tid & 3;
    const unsigned short* xp = xeb + (size_t)l * NRELS * HDIM + r * HDIM + hh * DM;
    const float* ap = att + (size_t)l * HDIM + hh * DM;
    float s = 0.f;
    #pragma unroll 8
    for (int c = 0; c < DM; ++c) s += ap[c] * b2f(xp[c]);
    be[tid] = 0.6f * s;
}

// ---------------- GEMM + fused ab: xl = h@Wl+bl, xr = h@Wr+br,
//                  ab[n][h] = 0.6 att_h.xl[n], ab[n][4+h] = 0.6 att_h.xr[n] -------------
__global__ __launch_bounds__(256) void gemm_xlxr_ab_kernel(
    const unsigned short* __restrict__ hb,        // [NN,128] bf16
    const unsigned short* __restrict__ WtL,       // [512][128] bf16 (transposed)
    const unsigned short* __restrict__ WtR,
    const float* __restrict__ bl, const float* __restrict__ br,
    const float* __restrict__ att_l,              // [512]
    unsigned short* __restrict__ xl, unsigned short* __restrict__ xr,
    float* __restrict__ ab) {
    int w = threadIdx.x >> 6, lane = threadIdx.x & 63;   // wave w owns head w (cols w*128..)
    int m0 = blockIdx.x * 16;
    int colL = lane & 15, kg = lane >> 4;

    frag8 a[4];
    const unsigned short* arow = hb + (size_t)(m0 + colL) * DM;   // A row = lane&15
    #pragma unroll
    for (int kc = 0; kc < 4; ++kc) {
        uint4 raw = *(const uint4*)(arow + kc * 32 + kg * 8);
        a[kc] = __builtin_bit_cast(frag8, raw);
    }

    float prow[2][4] = {{0.f, 0.f, 0.f, 0.f}, {0.f, 0.f, 0.f, 0.f}};
    #pragma unroll
    for (int mat = 0; mat < 2; ++mat) {
        const unsigned short* Wt = mat ? WtR : WtL;
        const float* bias = mat ? br : bl;
        unsigned short* out = mat ? xr : xl;
        #pragma unroll
        for (int nt = 0; nt < 8; ++nt) {
            int col = w * 128 + nt * 16 + colL;
            f32x4 acc = {0.f, 0.f, 0.f, 0.f};
            #pragma unroll
            for (int kc = 0; kc < 4; ++kc) {
                uint4 raw = *(const uint4*)(Wt + (size_t)col * DM + kc * 32 + kg * 8);
                frag8 b = __builtin_bit_cast(frag8, raw);
                acc = __builtin_amdgcn_mfma_f32_16x16x32_bf16(a[kc], b, acc, 0, 0, 0);
            }
            float bb = bias[col];
            float ac = att_l[col];
            #pragma unroll
            for (int r = 0; r < 4; ++r) {
                float v = acc[r] + bb;
                int row = m0 + kg * 4 + r;
                out[(size_t)row * HDIM + col] = f2b(v);
                prow[mat][r] = fmaf(ac, v, prow[mat][r]);
            }
        }
    }
    // reduce prow over the 16 lanes (colL) within each kg group
    #pragma unroll
    for (int d = 1; d < 16; d <<= 1) {
        #pragma unroll
        for (int mat = 0; mat < 2; ++mat)
            #pragma unroll
            for (int r = 0; r < 4; ++r)
                prow[mat][r] += __shfl_xor(prow[mat][r], d, 64);
    }
    if (colL == 0) {
        #pragma unroll
        for (int mat = 0; mat < 2; ++mat)
            #pragma unroll
            for (int r = 0; r < 4; ++r)
                ab[(size_t)(m0 + kg * 4 + r) * 8 + mat * 4 + w] = 0.6f * prow[mat][r];
    }
}

// ------- fused per-node: logits + softmax + aggregate + mean + gelu + residual + LN -------
__device__ __forceinline__ float2 breduce2(float a, float b, float* red, int lane, int wid) {
    #pragma unroll
    for (int d = 1; d < 64; d <<= 1) {
        a += __shfl_xor(a, d, 64);
        b += __shfl_xor(b, d, 64);
    }
    if (lane == 0) { red[wid * 2 + 0] = a; red[wid * 2 + 1] = b; }
    __syncthreads();
    float2 r;
    r.x = red[0] + red[2];
    r.y = red[1] + red[3];
    __syncthreads();
    return r;
}

__global__ __launch_bounds__(128) void node_fused_kernel(
    const int* __restrict__ row_ptr, const int* __restrict__ perm,
    const int* __restrict__ ei,              // src = ei[e]
    const int* __restrict__ etype,
    const unsigned short* __restrict__ xl,   // [NN][512] bf16
    const unsigned short* __restrict__ xr,   // [NN][512] bf16
    const unsigned short* __restrict__ xeb_l,// [64][512] bf16 (this layer)
    const float* __restrict__ ab,            // [NN][8] f32
    const float* __restrict__ be_l,          // [64][4] f32 (this layer)
    const float* __restrict__ att_l,         // [512] (this layer)
    const float* __restrict__ h_in,          // [NN][128]
    const float* __restrict__ b_out, const float* __restrict__ ln_g,
    const float* __restrict__ ln_b,
    float* __restrict__ h_out,
    unsigned short* __restrict__ hb_out) {   // bf16 copy for next layer's GEMM
    int i = blockIdx.x;
    int t = threadIdx.x;                 // 0..127, owns channels 4t..4t+3 of 512
    int lane = t & 63, wid = t >> 6;
    int hh = t >> 5;                     // head
    __shared__ uint2 ox_l[128];          // {src*1024, rel*1024} byte offsets
    __shared__ float cl[128][4];         // per-edge linear term per head
    __shared__ float lsum[512];
    __shared__ float red[4];

    int beg = row_ptr[i], end = row_ptr[i + 1];

    ushort4 xrv = ((const ushort4*)(xr + (size_t)i * HDIM))[t];
    float xr0 = b2f(xrv.x), xr1 = b2f(xrv.y), xr2 = b2f(xrv.z), xr3 = b2f(xrv.w);
    float4 at = ((const float4*)att_l)[t];
    at.x *= 0.4f; at.y *= 0.4f; at.z *= 0.4f; at.w *= 0.4f;
    float4 bxv = ((const float4*)ab)[2 * i + 1];   // 0.6 att.xr_i  (per head)

    const char* xl_b = (const char*)xl;
    const char* xe_b = (const char*)xeb_l;
    const float* clp = &cl[0][0];
    uint t8 = (uint)t << 3;

    float ssum = 0.f;
    float acc0 = 0.f, acc1 = 0.f, acc2 = 0.f, acc3 = 0.f;

    for (int cb = beg; cb < end; cb += 128) {
        int mc = min(128, end - cb);
        if (t < mc) {
            int p = perm[cb + t];
            int s = ei[p];
            int r = etype[p];
            ox_l[t].x = (uint)s << 10;
            ox_l[t].y = (uint)r << 10;
            float4 a4  = ((const float4*)ab)[2 * s];
            float4 be4 = ((const float4*)be_l)[r];
            cl[t][0] = a4.x + bxv.x + be4.x;
            cl[t][1] = a4.y + bxv.y + be4.y;
            cl[t][2] = a4.z + bxv.z + be4.z;
            cl[t][3] = a4.w + bxv.w + be4.w;
        }
        __syncthreads();
        #pragma unroll 2
        for (int j = 0; j < mc; ++j) {
            uint2 oo = ox_l[j];
            float cj = clp[j * 4 + hh];
            uint2 vv = *(const uint2*)(xl_b + oo.x + t8);
            uint2 ev = *(const uint2*)(xe_b + oo.y + t8);
            float x0 = b2f_lo(vv.x), x1 = b2f_hi(vv.x);
            float x2 = b2f_lo(vv.y), x3 = b2f_hi(vv.y);
            float z0 = (x0 + xr0) + b2f_lo(ev.x);
            float z1 = (x1 + xr1) + b2f_hi(ev.x);
            float z2 = (x2 + xr2) + b2f_lo(ev.y);
            float z3 = (x3 + xr3) + b2f_hi(ev.y);
            float partial = fmaf(at.x, fabsf(z0),
                            fmaf(at.y, fabsf(z1),
                            fmaf(at.z, fabsf(z2), at.w * fabsf(z3))));
            #pragma unroll
            for (int d = 1; d < 32; d <<= 1) partial += __shfl_xor(partial, d, 64);
            float w = __expf(partial + cj);
            ssum += w;
            acc0 = fmaf(w, x0, acc0);
            acc1 = fmaf(w, x1, acc1);
            acc2 = fmaf(w, x2, acc2);
            acc3 = fmaf(w, x3, acc3);
        }
        __syncthreads();
    }

    float invs = (ssum > 0.f) ? 1.f / ssum : 0.f;
    lsum[4 * t + 0] = acc0 * invs;
    lsum[4 * t + 1] = acc1 * invs;
    lsum[4 * t + 2] = acc2 * invs;
    lsum[4 * t + 3] = acc3 * invs;
    __syncthreads();

    int c = t;
    float o = (lsum[c] + lsum[128 + c] + lsum[256 + c] + lsum[384 + c]) * 0.25f + b_out[c];
    float ge = 0.5f * o * (1.f + erff(o * 0.70710678118654752f));
    float y = h_in[(size_t)i * DM + c] + ge;

    float2 r = breduce2(y, y * y, red, lane, wid);
    float mean = r.x * (1.f / 128.f);
    float var = r.y * (1.f / 128.f) - mean * mean;
    float rs = rsqrtf(var + 1e-5f);
    float out = (y - mean) * rs * ln_g[c] + ln_b[c];
    h_out[(size_t)i * DM + c] = out;
    hb_out[(size_t)i * DM + c] = f2b(out);
}

// ---------------- launch ----------------
extern "C" void kernel_launch(void* const* d_in, const int* in_sizes, int n_in,
                              void* d_out, int out_size, void* d_ws, size_t ws_size,
                              hipStream_t stream) {
    const float* x_flat   = (const float*)d_in[0];
    const int*   edge_idx = (const int*)d_in[1];
    const int*   edge_ty  = (const int*)d_in[2];
    const float* rel_emb  = (const float*)d_in[3];
    const float* Wl       = (const float*)d_in[4];
    const float* bl       = (const float*)d_in[5];
    const float* Wr       = (const float*)d_in[6];
    const float* br       = (const float*)d_in[7];
    const float* We       = (const float*)d_in[8];
    const float* att      = (const float*)d_in[9];
    const float* b_out    = (const float*)d_in[10];
    const float* ln_g     = (const float*)d_in[11];
    const float* ln_b     = (const float*)d_in[12];

    char* p = (char*)d_ws;
    auto carve = [&](size_t bytes) {
        void* r = (void*)p;
        p += (bytes + 255) & ~(size_t)255;
        return r;
    };
    unsigned short* xl     = (unsigned short*)carve((size_t)NN * HDIM * 2);
    unsigned short* xr     = (unsigned short*)carve((size_t)NN * HDIM * 2);
    float*          h1     = (float*)carve((size_t)NN * DM * 4);
    unsigned short* hb     = (unsigned short*)carve((size_t)NN * DM * 2);
    unsigned short* Wt     = (unsigned short*)carve((size_t)4 * DM * HDIM * 2);
    unsigned short* xeb    = (unsigned short*)carve((size_t)LAYERS * NRELS * HDIM * 2);
    float*          ab     = (float*)carve((size_t)NN * 8 * 4);
    float*          be     = (float*)carve((size_t)LAYERS * NRELS * NH * 4);
    int*            row_ptr= (int*)carve((size_t)(NN + 1) * 4);
    int*            counts = (int*)carve((size_t)NN * 4);
    int*            cursor = (int*)carve((size_t)NN * 4);
    int*            perm   = (int*)carve((size_t)EE * 4);

    const int* dst = edge_idx + EE;

    // CSR build
    hipMemsetAsync(counts, 0, (size_t)NN * 4, stream);
    count_kernel<<<(EE + 255) / 256, 256, 0, stream>>>(dst, counts);
    scan_kernel<<<1, 1024, 0, stream>>>(counts, row_ptr, NN);
    cursor_init_kernel<<<(NN + 255) / 256, 256, 0, stream>>>(row_ptr, cursor);
    scatter_kernel<<<(EE + 255) / 256, 256, 0, stream>>>(dst, cursor, perm);

    // weight prep
    for (int l = 0; l < LAYERS; ++l) {
        wconv_kernel<<<(DM * HDIM + 255) / 256, 256, 0, stream>>>(
            Wl + (size_t)l * DM * HDIM, Wt + (size_t)(l * 2 + 0) * DM * HDIM);
        wconv_kernel<<<(DM * HDIM + 255) / 256, 256, 0, stream>>>(
            Wr + (size_t)l * DM * HDIM, Wt + (size_t)(l * 2 + 1) * DM * HDIM);
    }
    xe_kernel<<<(LAYERS * NRELS * HDIM + 255) / 256, 256, 0, stream>>>(rel_emb, We, xeb);
    be_kernel<<<(LAYERS * NRELS * NH + 255) / 256, 256, 0, stream>>>(xeb, att, be);
    hb_kernel<<<(NN * DM / 4 + 255) / 256, 256, 0, stream>>>(x_flat, hb, NN * DM / 4);

    const float* h_cur = x_flat;
    for (int l = 0; l < LAYERS; ++l) {
        float* h_next = (l == LAYERS - 1) ? (float*)d_out : h1;
        gemm_xlxr_ab_kernel<<<NN / 16, 256, 0, stream>>>(
            hb,
            Wt + (size_t)(l * 2 + 0) * DM * HDIM,
            Wt + (size_t)(l * 2 + 1) * DM * HDIM,
            bl + (size_t)l * HDIM, br + (size_t)l * HDIM,
            att + (size_t)l * HDIM,
            xl, xr, ab);
        node_fused_kernel<<<NN, 128, 0, stream>>>(
            row_ptr, perm, edge_idx, edge_ty, xl, xr,
            xeb + (size_t)l * NRELS * HDIM,
            ab, be + (size_t)l * NRELS * NH,
            att + (size_t)l * HDIM,
            h_cur,
            b_out + (size_t)l * DM, ln_g + (size_t)l * DM, ln_b + (size_t)l * DM,
            h_next, hb);
        h_cur = h_next;
    }
}

// Round 5
// 660.683 us; speedup vs baseline: 1.7987x; 1.1570x over previous
//
#include <hip/hip_runtime.h>
#include <hip/hip_bf16.h>

#define NN 50000
#define DM 128
#define EE 800000
#define NH 4
#define HDIM 512      // NH * DM
#define NRELS 64
#define RDIM 64
#define LAYERS 2

typedef short frag8 __attribute__((ext_vector_type(8)));   // 8 bf16 (bits)
typedef float f32x4 __attribute__((ext_vector_type(4)));
typedef float f32x2 __attribute__((ext_vector_type(2)));

__device__ __forceinline__ float b2f(unsigned short u) {
    unsigned v = ((unsigned)u) << 16;
    union { unsigned u; float f; } c; c.u = v; return c.f;
}
__device__ __forceinline__ float b2f_lo(unsigned u) {
    union { unsigned u; float f; } c; c.u = u << 16; return c.f;
}
__device__ __forceinline__ float b2f_hi(unsigned u) {
    union { unsigned u; float f; } c; c.u = u & 0xFFFF0000u; return c.f;
}
__device__ __forceinline__ unsigned short f2b(float f) {
    union { float f; unsigned u; } c; c.f = f;
    unsigned u = c.u;
    u += 0x7FFFu + ((u >> 16) & 1u);   // round-to-nearest-even
    return (unsigned short)(u >> 16);
}

// ---------------- CSR build ----------------
__global__ void count_kernel(const int* __restrict__ dst, int* __restrict__ counts) {
    int e = blockIdx.x * 256 + threadIdx.x;
    if (e < EE) atomicAdd(&counts[dst[e]], 1);
}

__global__ void scan_kernel(const int* __restrict__ counts, int* __restrict__ row_ptr,
                            int* __restrict__ cursor, int n) {
    __shared__ int wsum[16];
    __shared__ int woff[17];
    int t = threadIdx.x;
    int lane = t & 63, wid = t >> 6;
    int carry = 0;
    if (t == 0) row_ptr[0] = 0;
    for (int base = 0; base < n; base += 1024) {
        int idx = base + t;
        int x = (idx < n) ? counts[idx] : 0;
        int incl = x;
        #pragma unroll
        for (int d = 1; d < 64; d <<= 1) {
            int y = __shfl_up(incl, d, 64);
            if (lane >= d) incl += y;
        }
        if (lane == 63) wsum[wid] = incl;
        __syncthreads();
        if (t == 0) {
            int s = 0;
            for (int w = 0; w < 16; ++w) { woff[w] = s; s += wsum[w]; }
            woff[16] = s;
        }
        __syncthreads();
        if (idx < n) {
            int v = carry + woff[wid] + incl;
            row_ptr[idx + 1] = v;
            cursor[idx] = v - x;       // exclusive prefix = initial cursor
        }
        carry += woff[16];
        __syncthreads();
    }
}

__global__ void scatter_kernel(const int* __restrict__ dst, int* __restrict__ cursor,
                               int* __restrict__ perm) {
    int e = blockIdx.x * 256 + threadIdx.x;
    if (e < EE) {
        int p = atomicAdd(&cursor[dst[e]], 1);
        perm[p] = e;
    }
}

// ---------------- prep kernels ----------------
__global__ void wconv_kernel(const float* __restrict__ W, unsigned short* __restrict__ Wt) {
    int idx = blockIdx.x * 256 + threadIdx.x;
    if (idx >= DM * HDIM) return;
    int c = idx >> 7, k = idx & 127;            // Wt[c][k] = W[k][c]
    Wt[idx] = f2b(W[k * HDIM + c]);
}

__global__ void hb_kernel(const float* __restrict__ h, unsigned short* __restrict__ hb, int n4) {
    int idx = blockIdx.x * 256 + threadIdx.x;
    if (idx >= n4) return;
    float4 v = ((const float4*)h)[idx];
    ushort4 o;
    o.x = f2b(v.x); o.y = f2b(v.y); o.z = f2b(v.z); o.w = f2b(v.w);
    ((ushort4*)hb)[idx] = o;
}

__global__ void xe_kernel(const float* __restrict__ rel_emb,  // [64][64]
                          const float* __restrict__ We,        // [2][64][512]
                          float* __restrict__ xef) {           // [2][64][512] f32
    int idx = blockIdx.x * 256 + threadIdx.x;
    if (idx >= LAYERS * NRELS * HDIM) return;
    int l  = idx / (NRELS * HDIM);
    int r  = (idx / HDIM) & (NRELS - 1);
    int hc = idx & (HDIM - 1);
    const float* Wel = We + (size_t)l * RDIM * HDIM;
    float s = 0.f;
    #pragma unroll 8
    for (int d = 0; d < RDIM; ++d) s += rel_emb[r * RDIM + d] * Wel[d * HDIM + hc];
    xef[idx] = s;
}

// be[l][r][h] = 0.6 * sum_c att[l][h][c] * xe[l][r][h*128+c]
__global__ void be_kernel(const float* __restrict__ xef, const float* __restrict__ att,
                          float* __restrict__ be) {
    int tid = blockIdx.x * 256 + threadIdx.x;
    if (tid >= LAYERS * NRELS * NH) return;
    int l = tid >> 8;
    int r = (tid >> 2) & 63;
    int hh = tid & 3;
    const float* xp = xef + (size_t)l * NRELS * HDIM + r * HDIM + hh * DM;
    const float* ap = att + (size_t)l * HDIM + hh * DM;
    float s = 0.f;
    #pragma unroll 8
    for (int c = 0; c < DM; ++c) s += ap[c] * xp[c];
    be[tid] = 0.6f * s;
}

// ---------------- GEMM (M=32 tile) + fused ab ----------------
__global__ __launch_bounds__(256) void gemm_xlxr_ab_kernel(
    const unsigned short* __restrict__ hb,        // [NN,128] bf16
    const unsigned short* __restrict__ WtL,       // [512][128] bf16 (transposed)
    const unsigned short* __restrict__ WtR,
    const float* __restrict__ bl, const float* __restrict__ br,
    const float* __restrict__ att_l,              // [512]
    unsigned short* __restrict__ xl, unsigned short* __restrict__ xr,
    float* __restrict__ ab) {
    int w = threadIdx.x >> 6, lane = threadIdx.x & 63;   // wave w owns head w (cols w*128..)
    int m0 = blockIdx.x * 32;
    int colL = lane & 15, kg = lane >> 4;

    frag8 a[2][4];
    #pragma unroll
    for (int mt = 0; mt < 2; ++mt) {
        int row = m0 + mt * 16 + colL;
        if (row >= NN) row = NN - 1;
        const unsigned short* arow = hb + (size_t)row * DM;
        #pragma unroll
        for (int kc = 0; kc < 4; ++kc) {
            uint4 raw = *(const uint4*)(arow + kc * 32 + kg * 8);
            a[mt][kc] = __builtin_bit_cast(frag8, raw);
        }
    }

    float prow[2][2][4];   // [mt][mat][r]
    #pragma unroll
    for (int mt = 0; mt < 2; ++mt)
        #pragma unroll
        for (int mat = 0; mat < 2; ++mat)
            #pragma unroll
            for (int r = 0; r < 4; ++r) prow[mt][mat][r] = 0.f;

    #pragma unroll
    for (int mat = 0; mat < 2; ++mat) {
        const unsigned short* Wt = mat ? WtR : WtL;
        const float* bias = mat ? br : bl;
        unsigned short* out = mat ? xr : xl;
        #pragma unroll
        for (int nt = 0; nt < 8; ++nt) {
            int col = w * 128 + nt * 16 + colL;
            f32x4 acc0 = {0.f, 0.f, 0.f, 0.f};
            f32x4 acc1 = {0.f, 0.f, 0.f, 0.f};
            #pragma unroll
            for (int kc = 0; kc < 4; ++kc) {
                uint4 raw = *(const uint4*)(Wt + (size_t)col * DM + kc * 32 + kg * 8);
                frag8 b = __builtin_bit_cast(frag8, raw);
                acc0 = __builtin_amdgcn_mfma_f32_16x16x32_bf16(a[0][kc], b, acc0, 0, 0, 0);
                acc1 = __builtin_amdgcn_mfma_f32_16x16x32_bf16(a[1][kc], b, acc1, 0, 0, 0);
            }
            float bb = bias[col];
            float ac = att_l[col];
            #pragma unroll
            for (int r = 0; r < 4; ++r) {
                float v0 = acc0[r] + bb;
                float v1 = acc1[r] + bb;
                int row0 = m0 + kg * 4 + r;
                int row1 = row0 + 16;
                if (row0 < NN) out[(size_t)row0 * HDIM + col] = f2b(v0);
                if (row1 < NN) out[(size_t)row1 * HDIM + col] = f2b(v1);
                prow[0][mat][r] = fmaf(ac, v0, prow[0][mat][r]);
                prow[1][mat][r] = fmaf(ac, v1, prow[1][mat][r]);
            }
        }
    }
    // reduce prow over the 16 colL lanes
    #pragma unroll
    for (int d = 1; d < 16; d <<= 1) {
        #pragma unroll
        for (int mt = 0; mt < 2; ++mt)
            #pragma unroll
            for (int mat = 0; mat < 2; ++mat)
                #pragma unroll
                for (int r = 0; r < 4; ++r)
                    prow[mt][mat][r] += __shfl_xor(prow[mt][mat][r], d, 64);
    }
    if (colL == 0) {
        #pragma unroll
        for (int mt = 0; mt < 2; ++mt) {
            int row = m0 + mt * 16 + kg * 4;
            #pragma unroll
            for (int mat = 0; mat < 2; ++mat)
                #pragma unroll
                for (int r = 0; r < 4; ++r)
                    if (row + r < NN)
                        ab[(size_t)(row + r) * 8 + mat * 4 + w] = 0.6f * prow[mt][mat][r];
        }
    }
}

// ------- fused per-node: logits + softmax + aggregate + mean + gelu + residual + LN -------
// Block = 128 threads = 2 waves. Each wave processes half the edges; each lane owns
// 8 channels (lane*8 .. lane*8+7); head = lane>>4 (16 lanes x 8 ch = 128 ch per head).
__global__ __launch_bounds__(128) void node_fused_kernel(
    const int* __restrict__ row_ptr, const int* __restrict__ perm,
    const int* __restrict__ ei,              // src = ei[e]
    const int* __restrict__ etype,
    const unsigned short* __restrict__ xl,   // [NN][512] bf16
    const unsigned short* __restrict__ xr,   // [NN][512] bf16
    const float* __restrict__ xef_l,         // [64][512] f32 (this layer)
    const float* __restrict__ ab,            // [NN][8] f32
    const float* __restrict__ be_l,          // [64][4] f32 (this layer)
    const float* __restrict__ att_l,         // [512] (this layer)
    const float* __restrict__ h_in,          // [NN][128]
    const float* __restrict__ b_out, const float* __restrict__ ln_g,
    const float* __restrict__ ln_b,
    float* __restrict__ h_out,
    unsigned short* __restrict__ hb_out) {
    int i = blockIdx.x;
    int t = threadIdx.x;                 // 0..127
    int w = t >> 6, l = t & 63;
    int hh = l >> 4;                     // head of this lane
    __shared__ uint2 ox_l[128];          // {src*1024, rel*2048} byte offsets
    __shared__ float cl[128][4];         // per-edge linear logit term per head
    __shared__ float lsum[2][512];
    __shared__ float ssum_s[2][4];
    __shared__ float inv_s[4];
    __shared__ float red[4];

    int beg = row_ptr[i], end = row_ptr[i + 1];

    // per-lane 8 channels
    uint4 xrv = *(const uint4*)(xr + (size_t)i * HDIM + l * 8);
    f32x2 xrp[4];
    xrp[0] = f32x2{b2f_lo(xrv.x), b2f_hi(xrv.x)};
    xrp[1] = f32x2{b2f_lo(xrv.y), b2f_hi(xrv.y)};
    xrp[2] = f32x2{b2f_lo(xrv.z), b2f_hi(xrv.z)};
    xrp[3] = f32x2{b2f_lo(xrv.w), b2f_hi(xrv.w)};
    float4 at0 = ((const float4*)(att_l + l * 8))[0];
    float4 at1 = ((const float4*)(att_l + l * 8))[1];
    float atv[8] = {at0.x * 0.4f, at0.y * 0.4f, at0.z * 0.4f, at0.w * 0.4f,
                    at1.x * 0.4f, at1.y * 0.4f, at1.z * 0.4f, at1.w * 0.4f};
    float4 bxv = ((const float4*)ab)[2 * i + 1];   // 0.6 att.xr_i per head

    const char* xl_b = (const char*)xl;
    const char* xe_b = (const char*)xef_l;
    uint l16 = (uint)l << 4, l32 = (uint)l << 5;

    float ss = 0.f;
    f32x2 acc[4];
    acc[0] = f32x2{0.f, 0.f}; acc[1] = f32x2{0.f, 0.f};
    acc[2] = f32x2{0.f, 0.f}; acc[3] = f32x2{0.f, 0.f};

    for (int cb = beg; cb < end; cb += 128) {
        int mc = min(128, end - cb);
        if (t < mc) {
            int p = perm[cb + t];
            int s = ei[p];
            int r = etype[p];
            ox_l[t].x = (uint)s << 10;
            ox_l[t].y = (uint)r << 11;
            float4 a4  = ((const float4*)ab)[2 * s];
            float4 be4 = ((const float4*)be_l)[r];
            cl[t][0] = a4.x + bxv.x + be4.x;
            cl[t][1] = a4.y + bxv.y + be4.y;
            cl[t][2] = a4.z + bxv.z + be4.z;
            cl[t][3] = a4.w + bxv.w + be4.w;
        }
        __syncthreads();
        for (int j = w; j < mc; j += 2) {
            uint2 oo = ox_l[j];
            float cj = cl[j][hh];
            uint4 vv = *(const uint4*)(xl_b + oo.x + l16);
            const float* xerow = (const float*)(xe_b + oo.y);
            float4 e0 = *(const float4*)(xerow + l * 8);
            float4 e1 = *(const float4*)(xerow + l * 8 + 4);
            f32x2 xp0 = f32x2{b2f_lo(vv.x), b2f_hi(vv.x)};
            f32x2 xp1 = f32x2{b2f_lo(vv.y), b2f_hi(vv.y)};
            f32x2 xp2 = f32x2{b2f_lo(vv.z), b2f_hi(vv.z)};
            f32x2 xp3 = f32x2{b2f_lo(vv.w), b2f_hi(vv.w)};
            f32x2 z0 = (xp0 + xrp[0]) + f32x2{e0.x, e0.y};
            f32x2 z1 = (xp1 + xrp[1]) + f32x2{e0.z, e0.w};
            f32x2 z2 = (xp2 + xrp[2]) + f32x2{e1.x, e1.y};
            f32x2 z3 = (xp3 + xrp[3]) + f32x2{e1.z, e1.w};
            float partial = fmaf(atv[0], fabsf(z0[0]),
                            fmaf(atv[1], fabsf(z0[1]),
                            fmaf(atv[2], fabsf(z1[0]),
                            fmaf(atv[3], fabsf(z1[1]),
                            fmaf(atv[4], fabsf(z2[0]),
                            fmaf(atv[5], fabsf(z2[1]),
                            fmaf(atv[6], fabsf(z3[0]), atv[7] * fabsf(z3[1]))))))));
            #pragma unroll
            for (int d = 1; d < 16; d <<= 1) partial += __shfl_xor(partial, d, 64);
            float we = __expf(partial + cj);
            ss += we;
            f32x2 wv = f32x2{we, we};
            acc[0] += wv * xp0;
            acc[1] += wv * xp1;
            acc[2] += wv * xp2;
            acc[3] += wv * xp3;
        }
        __syncthreads();
    }

    // merge the two waves' partials
    float* lw = &lsum[w][l * 8];
    lw[0] = acc[0][0]; lw[1] = acc[0][1]; lw[2] = acc[1][0]; lw[3] = acc[1][1];
    lw[4] = acc[2][0]; lw[5] = acc[2][1]; lw[6] = acc[3][0]; lw[7] = acc[3][1];
    if ((l & 15) == 0) ssum_s[w][hh] = ss;
    __syncthreads();
    if (t < 4) {
        float s = ssum_s[0][t] + ssum_s[1][t];
        inv_s[t] = (s > 0.f) ? 1.f / s : 0.f;
    }
    __syncthreads();

    int c = t;
    float o = 0.f;
    #pragma unroll
    for (int h = 0; h < 4; ++h)
        o = fmaf(lsum[0][h * 128 + c] + lsum[1][h * 128 + c], inv_s[h], o);
    o = o * 0.25f + b_out[c];
    float ge = 0.5f * o * (1.f + erff(o * 0.70710678118654752f));
    float y = h_in[(size_t)i * DM + c] + ge;

    // LN reduce over 128 threads
    float a = y, b = y * y;
    int lane = t & 63, wid = t >> 6;
    #pragma unroll
    for (int d = 1; d < 64; d <<= 1) {
        a += __shfl_xor(a, d, 64);
        b += __shfl_xor(b, d, 64);
    }
    if (lane == 0) { red[wid * 2 + 0] = a; red[wid * 2 + 1] = b; }
    __syncthreads();
    float mean = (red[0] + red[2]) * (1.f / 128.f);
    float var = (red[1] + red[3]) * (1.f / 128.f) - mean * mean;
    float rs = rsqrtf(var + 1e-5f);
    float out = (y - mean) * rs * ln_g[c] + ln_b[c];
    h_out[(size_t)i * DM + c] = out;
    hb_out[(size_t)i * DM + c] = f2b(out);
}

// ---------------- launch ----------------
extern "C" void kernel_launch(void* const* d_in, const int* in_sizes, int n_in,
                              void* d_out, int out_size, void* d_ws, size_t ws_size,
                              hipStream_t stream) {
    const float* x_flat   = (const float*)d_in[0];
    const int*   edge_idx = (const int*)d_in[1];
    const int*   edge_ty  = (const int*)d_in[2];
    const float* rel_emb  = (const float*)d_in[3];
    const float* Wl       = (const float*)d_in[4];
    const float* bl       = (const float*)d_in[5];
    const float* Wr       = (const float*)d_in[6];
    const float* br       = (const float*)d_in[7];
    const float* We       = (const float*)d_in[8];
    const float* att      = (const float*)d_in[9];
    const float* b_out    = (const float*)d_in[10];
    const float* ln_g     = (const float*)d_in[11];
    const float* ln_b     = (const float*)d_in[12];

    char* p = (char*)d_ws;
    auto carve = [&](size_t bytes) {
        void* r = (void*)p;
        p += (bytes + 255) & ~(size_t)255;
        return r;
    };
    unsigned short* xl     = (unsigned short*)carve((size_t)NN * HDIM * 2);
    unsigned short* xr     = (unsigned short*)carve((size_t)NN * HDIM * 2);
    float*          h1     = (float*)carve((size_t)NN * DM * 4);
    unsigned short* hb     = (unsigned short*)carve((size_t)NN * DM * 2);
    unsigned short* Wt     = (unsigned short*)carve((size_t)4 * DM * HDIM * 2);
    float*          xef    = (float*)carve((size_t)LAYERS * NRELS * HDIM * 4);
    float*          ab     = (float*)carve((size_t)NN * 8 * 4);
    float*          be     = (float*)carve((size_t)LAYERS * NRELS * NH * 4);
    int*            row_ptr= (int*)carve((size_t)(NN + 1) * 4);
    int*            counts = (int*)carve((size_t)NN * 4);
    int*            cursor = (int*)carve((size_t)NN * 4);
    int*            perm   = (int*)carve((size_t)EE * 4);

    const int* dst = edge_idx + EE;

    // CSR build
    hipMemsetAsync(counts, 0, (size_t)NN * 4, stream);
    count_kernel<<<(EE + 255) / 256, 256, 0, stream>>>(dst, counts);
    scan_kernel<<<1, 1024, 0, stream>>>(counts, row_ptr, cursor, NN);
    scatter_kernel<<<(EE + 255) / 256, 256, 0, stream>>>(dst, cursor, perm);

    // weight prep
    for (int l = 0; l < LAYERS; ++l) {
        wconv_kernel<<<(DM * HDIM + 255) / 256, 256, 0, stream>>>(
            Wl + (size_t)l * DM * HDIM, Wt + (size_t)(l * 2 + 0) * DM * HDIM);
        wconv_kernel<<<(DM * HDIM + 255) / 256, 256, 0, stream>>>(
            Wr + (size_t)l * DM * HDIM, Wt + (size_t)(l * 2 + 1) * DM * HDIM);
    }
    xe_kernel<<<(LAYERS * NRELS * HDIM + 255) / 256, 256, 0, stream>>>(rel_emb, We, xef);
    be_kernel<<<(LAYERS * NRELS * NH + 255) / 256, 256, 0, stream>>>(xef, att, be);
    hb_kernel<<<(NN * DM / 4 + 255) / 256, 256, 0, stream>>>(x_flat, hb, NN * DM / 4);

    const float* h_cur = x_flat;
    for (int l = 0; l < LAYERS; ++l) {
        float* h_next = (l == LAYERS - 1) ? (float*)d_out : h1;
        gemm_xlxr_ab_kernel<<<(NN + 31) / 32, 256, 0, stream>>>(
            hb,
            Wt + (size_t)(l * 2 + 0) * DM * HDIM,
            Wt + (size_t)(l * 2 + 1) * DM * HDIM,
            bl + (size_t)l * HDIM, br + (size_t)l * HDIM,
            att + (size_t)l * HDIM,
            xl, xr, ab);
        node_fused_kernel<<<NN, 128, 0, stream>>>(
            row_ptr, perm, edge_idx, edge_ty, xl, xr,
            xef + (size_t)l * NRELS * HDIM,
            ab, be + (size_t)l * NRELS * NH,
            att + (size_t)l * HDIM,
            h_cur,
            b_out + (size_t)l * DM, ln_g + (size_t)l * DM, ln_b + (size_t)l * DM,
            h_next, hb);
        h_cur = h_next;
    }
}

// Round 6
// 641.168 us; speedup vs baseline: 1.8534x; 1.0304x over previous
//
#include <hip/hip_runtime.h>
#include <hip/hip_bf16.h>

#define NN 50000
#define DM 128
#define EE 800000
#define NH 4
#define HDIM 512      // NH * DM
#define NRELS 64
#define RDIM 64
#define LAYERS 2
#define NB 196        // ceil(NN/256)

typedef short frag8 __attribute__((ext_vector_type(8)));   // 8 bf16 (bits)
typedef float f32x4 __attribute__((ext_vector_type(4)));
typedef float f32x2 __attribute__((ext_vector_type(2)));

__device__ __forceinline__ float b2f(unsigned short u) {
    unsigned v = ((unsigned)u) << 16;
    union { unsigned u; float f; } c; c.u = v; return c.f;
}
__device__ __forceinline__ float b2f_lo(unsigned u) {
    union { unsigned u; float f; } c; c.u = u << 16; return c.f;
}
__device__ __forceinline__ float b2f_hi(unsigned u) {
    union { unsigned u; float f; } c; c.u = u & 0xFFFF0000u; return c.f;
}
__device__ __forceinline__ unsigned short f2b(float f) {
    union { float f; unsigned u; } c; c.f = f;
    unsigned u = c.u;
    u += 0x7FFFu + ((u >> 16) & 1u);   // round-to-nearest-even
    return (unsigned short)(u >> 16);
}

// ---------------- CSR build ----------------
__global__ void count_kernel(const int* __restrict__ dst, int* __restrict__ counts) {
    int e = blockIdx.x * 256 + threadIdx.x;
    if (e < EE) atomicAdd(&counts[dst[e]], 1);
}

// pass 1: per-block (256-elem) sums
__global__ __launch_bounds__(256) void psum_kernel(const int* __restrict__ counts,
                                                   int* __restrict__ psums) {
    int idx = blockIdx.x * 256 + threadIdx.x;
    int x = (idx < NN) ? counts[idx] : 0;
    int lane = threadIdx.x & 63, wv = threadIdx.x >> 6;
    #pragma unroll
    for (int d = 1; d < 64; d <<= 1) x += __shfl_xor(x, d, 64);
    __shared__ int ws[4];
    if (lane == 0) ws[wv] = x;
    __syncthreads();
    if (threadIdx.x == 0) psums[blockIdx.x] = ws[0] + ws[1] + ws[2] + ws[3];
}

// pass 2: exclusive scan of NB partial sums (single block)
__global__ __launch_bounds__(256) void pscan_kernel(const int* __restrict__ psums,
                                                    int* __restrict__ offs,
                                                    int* __restrict__ row_ptr) {
    int t = threadIdx.x;
    int x = (t < NB) ? psums[t] : 0;
    int lane = t & 63, wv = t >> 6;
    int incl = x;
    #pragma unroll
    for (int d = 1; d < 64; d <<= 1) {
        int y = __shfl_up(incl, d, 64);
        if (lane >= d) incl += y;
    }
    __shared__ int ws[4];
    if (lane == 63) ws[wv] = incl;
    __syncthreads();
    int off = 0;
    for (int k = 0; k < wv; ++k) off += ws[k];
    if (t < NB) offs[t] = incl + off - x;   // exclusive
    if (t == 0) row_ptr[0] = 0;
}

// pass 3: per-block inclusive scan + offset -> row_ptr[idx+1], cursor[idx]
__global__ __launch_bounds__(256) void pfin_kernel(const int* __restrict__ counts,
                                                   const int* __restrict__ offs,
                                                   int* __restrict__ row_ptr,
                                                   int* __restrict__ cursor) {
    int idx = blockIdx.x * 256 + threadIdx.x;
    int x = (idx < NN) ? counts[idx] : 0;
    int lane = threadIdx.x & 63, wv = threadIdx.x >> 6;
    int incl = x;
    #pragma unroll
    for (int d = 1; d < 64; d <<= 1) {
        int y = __shfl_up(incl, d, 64);
        if (lane >= d) incl += y;
    }
    __shared__ int ws[4];
    if (lane == 63) ws[wv] = incl;
    __syncthreads();
    int off = offs[blockIdx.x];
    for (int k = 0; k < wv; ++k) off += ws[k];
    if (idx < NN) {
        int v = off + incl;
        row_ptr[idx + 1] = v;
        cursor[idx] = v - x;
    }
}

__global__ void scatter_kernel(const int* __restrict__ dst, int* __restrict__ cursor,
                               int* __restrict__ perm) {
    int e = blockIdx.x * 256 + threadIdx.x;
    if (e < EE) {
        int p = atomicAdd(&cursor[dst[e]], 1);
        perm[p] = e;
    }
}

// ---------------- prep kernels ----------------
// all 4 weight matrices in one dispatch: m = l*2 + (0:Wl,1:Wr)
__global__ void wconv_all_kernel(const float* __restrict__ Wl, const float* __restrict__ Wr,
                                 unsigned short* __restrict__ Wt) {
    int idx = blockIdx.x * 256 + threadIdx.x;
    if (idx >= 4 * DM * HDIM) return;
    int m = idx >> 16;          // 65536 elems per matrix
    int r = idx & 65535;
    int c = r >> 7, k = r & 127;
    int l = m >> 1;
    const float* W = (m & 1) ? Wr : Wl;
    Wt[idx] = f2b(W[(size_t)l * DM * HDIM + k * HDIM + c]);
}

__global__ void hb_kernel(const float* __restrict__ h, unsigned short* __restrict__ hb, int n4) {
    int idx = blockIdx.x * 256 + threadIdx.x;
    if (idx >= n4) return;
    float4 v = ((const float4*)h)[idx];
    ushort4 o;
    o.x = f2b(v.x); o.y = f2b(v.y); o.z = f2b(v.z); o.w = f2b(v.w);
    ((ushort4*)hb)[idx] = o;
}

__global__ void xe_kernel(const float* __restrict__ rel_emb,  // [64][64]
                          const float* __restrict__ We,        // [2][64][512]
                          float* __restrict__ xef) {           // [2][64][512] f32
    int idx = blockIdx.x * 256 + threadIdx.x;
    if (idx >= LAYERS * NRELS * HDIM) return;
    int l  = idx / (NRELS * HDIM);
    int r  = (idx / HDIM) & (NRELS - 1);
    int hc = idx & (HDIM - 1);
    const float* Wel = We + (size_t)l * RDIM * HDIM;
    float s = 0.f;
    #pragma unroll 8
    for (int d = 0; d < RDIM; ++d) s += rel_emb[r * RDIM + d] * Wel[d * HDIM + hc];
    xef[idx] = s;
}

// be[l][r][h] = 0.6 * sum_c att[l][h][c] * xe[l][r][h*128+c]
__global__ void be_kernel(const float* __restrict__ xef, const float* __restrict__ att,
                          float* __restrict__ be) {
    int tid = blockIdx.x * 256 + threadIdx.x;
    if (tid >= LAYERS * NRELS * NH) return;
    int l = tid >> 8;
    int r = (tid >> 2) & 63;
    int hh = tid & 3;
    const float* xp = xef + (size_t)l * NRELS * HDIM + r * HDIM + hh * DM;
    const float* ap = att + (size_t)l * HDIM + hh * DM;
    float s = 0.f;
    #pragma unroll 8
    for (int c = 0; c < DM; ++c) s += ap[c] * xp[c];
    be[tid] = 0.6f * s;
}

// ---------------- GEMM (M=32 tile) + fused ab ----------------
__global__ __launch_bounds__(256) void gemm_xlxr_ab_kernel(
    const unsigned short* __restrict__ hb,        // [NN,128] bf16
    const unsigned short* __restrict__ WtL,       // [512][128] bf16 (transposed)
    const unsigned short* __restrict__ WtR,
    const float* __restrict__ bl, const float* __restrict__ br,
    const float* __restrict__ att_l,              // [512]
    unsigned short* __restrict__ xl, unsigned short* __restrict__ xr,
    float* __restrict__ ab) {
    int w = threadIdx.x >> 6, lane = threadIdx.x & 63;   // wave w owns head w
    int m0 = blockIdx.x * 32;
    int colL = lane & 15, kg = lane >> 4;

    frag8 a[2][4];
    #pragma unroll
    for (int mt = 0; mt < 2; ++mt) {
        int row = m0 + mt * 16 + colL;
        if (row >= NN) row = NN - 1;
        const unsigned short* arow = hb + (size_t)row * DM;
        #pragma unroll
        for (int kc = 0; kc < 4; ++kc) {
            uint4 raw = *(const uint4*)(arow + kc * 32 + kg * 8);
            a[mt][kc] = __builtin_bit_cast(frag8, raw);
        }
    }

    float prow[2][2][4];   // [mt][mat][r]
    #pragma unroll
    for (int mt = 0; mt < 2; ++mt)
        #pragma unroll
        for (int mat = 0; mat < 2; ++mat)
            #pragma unroll
            for (int r = 0; r < 4; ++r) prow[mt][mat][r] = 0.f;

    #pragma unroll
    for (int mat = 0; mat < 2; ++mat) {
        const unsigned short* Wt = mat ? WtR : WtL;
        const float* bias = mat ? br : bl;
        unsigned short* out = mat ? xr : xl;
        #pragma unroll
        for (int nt = 0; nt < 8; ++nt) {
            int col = w * 128 + nt * 16 + colL;
            f32x4 acc0 = {0.f, 0.f, 0.f, 0.f};
            f32x4 acc1 = {0.f, 0.f, 0.f, 0.f};
            #pragma unroll
            for (int kc = 0; kc < 4; ++kc) {
                uint4 raw = *(const uint4*)(Wt + (size_t)col * DM + kc * 32 + kg * 8);
                frag8 b = __builtin_bit_cast(frag8, raw);
                acc0 = __builtin_amdgcn_mfma_f32_16x16x32_bf16(a[0][kc], b, acc0, 0, 0, 0);
                acc1 = __builtin_amdgcn_mfma_f32_16x16x32_bf16(a[1][kc], b, acc1, 0, 0, 0);
            }
            float bb = bias[col];
            float ac = att_l[col];
            #pragma unroll
            for (int r = 0; r < 4; ++r) {
                float v0 = acc0[r] + bb;
                float v1 = acc1[r] + bb;
                int row0 = m0 + kg * 4 + r;
                int row1 = row0 + 16;
                if (row0 < NN) out[(size_t)row0 * HDIM + col] = f2b(v0);
                if (row1 < NN) out[(size_t)row1 * HDIM + col] = f2b(v1);
                prow[0][mat][r] = fmaf(ac, v0, prow[0][mat][r]);
                prow[1][mat][r] = fmaf(ac, v1, prow[1][mat][r]);
            }
        }
    }
    #pragma unroll
    for (int d = 1; d < 16; d <<= 1) {
        #pragma unroll
        for (int mt = 0; mt < 2; ++mt)
            #pragma unroll
            for (int mat = 0; mat < 2; ++mat)
                #pragma unroll
                for (int r = 0; r < 4; ++r)
                    prow[mt][mat][r] += __shfl_xor(prow[mt][mat][r], d, 64);
    }
    if (colL == 0) {
        #pragma unroll
        for (int mt = 0; mt < 2; ++mt) {
            int row = m0 + mt * 16 + kg * 4;
            #pragma unroll
            for (int mat = 0; mat < 2; ++mat)
                #pragma unroll
                for (int r = 0; r < 4; ++r)
                    if (row + r < NN)
                        ab[(size_t)(row + r) * 8 + mat * 4 + w] = 0.6f * prow[mt][mat][r];
        }
    }
}

// ------- fused per-node: logits + softmax + aggregate + mean + gelu + residual + LN -------
// Block = 128 threads = 2 waves. Wave w takes a contiguous half of each edge chunk,
// 4-deep software-pipelined. Each lane owns 8 channels; head = lane>>4.
#define EDGE_LOAD(k, jj)                                              \
    uint2 oo##k = ox_l[jj];                                           \
    float cj##k = cl[jj][hh];                                         \
    uint4 vv##k = *(const uint4*)(xl_b + oo##k.x + l16);              \
    float4 e0##k = *(const float4*)(xe_b + oo##k.y + l32);            \
    float4 e1##k = *(const float4*)(xe_b + oo##k.y + l32 + 16);

#define EDGE_PROC(k) {                                                \
    f32x2 xp0 = f32x2{b2f_lo(vv##k.x), b2f_hi(vv##k.x)};              \
    f32x2 xp1 = f32x2{b2f_lo(vv##k.y), b2f_hi(vv##k.y)};              \
    f32x2 xp2 = f32x2{b2f_lo(vv##k.z), b2f_hi(vv##k.z)};              \
    f32x2 xp3 = f32x2{b2f_lo(vv##k.w), b2f_hi(vv##k.w)};              \
    f32x2 z0 = (xp0 + xrp0) + f32x2{e0##k.x, e0##k.y};                \
    f32x2 z1 = (xp1 + xrp1) + f32x2{e0##k.z, e0##k.w};                \
    f32x2 z2 = (xp2 + xrp2) + f32x2{e1##k.x, e1##k.y};                \
    f32x2 z3 = (xp3 + xrp3) + f32x2{e1##k.z, e1##k.w};                \
    float partial = fmaf(atv[0], fabsf(z0[0]),                        \
                    fmaf(atv[1], fabsf(z0[1]),                        \
                    fmaf(atv[2], fabsf(z1[0]),                        \
                    fmaf(atv[3], fabsf(z1[1]),                        \
                    fmaf(atv[4], fabsf(z2[0]),                        \
                    fmaf(atv[5], fabsf(z2[1]),                        \
                    fmaf(atv[6], fabsf(z3[0]), atv[7] * fabsf(z3[1])))))))); \
    _Pragma("unroll")                                                 \
    for (int d = 1; d < 16; d <<= 1) partial += __shfl_xor(partial, d, 64); \
    float we = __expf(partial + cj##k);                               \
    ss += we;                                                         \
    f32x2 wv = f32x2{we, we};                                         \
    acc0v += wv * xp0;                                                \
    acc1v += wv * xp1;                                                \
    acc2v += wv * xp2;                                                \
    acc3v += wv * xp3; }

__global__ __launch_bounds__(128) void node_fused_kernel(
    const int* __restrict__ row_ptr, const int* __restrict__ perm,
    const int* __restrict__ ei,              // src = ei[e]
    const int* __restrict__ etype,
    const unsigned short* __restrict__ xl,   // [NN][512] bf16
    const unsigned short* __restrict__ xr,   // [NN][512] bf16
    const float* __restrict__ xef_l,         // [64][512] f32 (this layer)
    const float* __restrict__ ab,            // [NN][8] f32
    const float* __restrict__ be_l,          // [64][4] f32 (this layer)
    const float* __restrict__ att_l,         // [512] (this layer)
    const float* __restrict__ h_in,          // [NN][128]
    const float* __restrict__ b_out, const float* __restrict__ ln_g,
    const float* __restrict__ ln_b,
    float* __restrict__ h_out,
    unsigned short* __restrict__ hb_out) {
    int i = blockIdx.x;
    int t = threadIdx.x;                 // 0..127
    int w = t >> 6, l = t & 63;
    int hh = l >> 4;                     // head of this lane
    __shared__ uint2 ox_l[128];          // {src*1024, rel*2048} byte offsets
    __shared__ float cl[128][4];         // per-edge linear logit term per head
    __shared__ float lsum[2][512];
    __shared__ float ssum_s[2][4];
    __shared__ float inv_s[4];
    __shared__ float red[4];

    int beg = row_ptr[i], end = row_ptr[i + 1];

    uint4 xrv = *(const uint4*)(xr + (size_t)i * HDIM + l * 8);
    f32x2 xrp0 = f32x2{b2f_lo(xrv.x), b2f_hi(xrv.x)};
    f32x2 xrp1 = f32x2{b2f_lo(xrv.y), b2f_hi(xrv.y)};
    f32x2 xrp2 = f32x2{b2f_lo(xrv.z), b2f_hi(xrv.z)};
    f32x2 xrp3 = f32x2{b2f_lo(xrv.w), b2f_hi(xrv.w)};
    float4 at0 = ((const float4*)(att_l + l * 8))[0];
    float4 at1 = ((const float4*)(att_l + l * 8))[1];
    float atv[8] = {at0.x * 0.4f, at0.y * 0.4f, at0.z * 0.4f, at0.w * 0.4f,
                    at1.x * 0.4f, at1.y * 0.4f, at1.z * 0.4f, at1.w * 0.4f};
    float4 bxv = ((const float4*)ab)[2 * i + 1];   // 0.6 att.xr_i per head

    const char* xl_b = (const char*)xl;
    const char* xe_b = (const char*)xef_l;
    uint l16 = (uint)l << 4, l32 = (uint)l << 5;

    float ss = 0.f;
    f32x2 acc0v = f32x2{0.f, 0.f}, acc1v = f32x2{0.f, 0.f};
    f32x2 acc2v = f32x2{0.f, 0.f}, acc3v = f32x2{0.f, 0.f};

    for (int cb = beg; cb < end; cb += 128) {
        int mc = min(128, end - cb);
        if (t < mc) {
            int p = perm[cb + t];
            int s = ei[p];
            int r = etype[p];
            ox_l[t].x = (uint)s << 10;
            ox_l[t].y = (uint)r << 11;
            float4 a4  = ((const float4*)ab)[2 * s];
            float4 be4 = ((const float4*)be_l)[r];
            cl[t][0] = a4.x + bxv.x + be4.x;
            cl[t][1] = a4.y + bxv.y + be4.y;
            cl[t][2] = a4.z + bxv.z + be4.z;
            cl[t][3] = a4.w + bxv.w + be4.w;
        }
        __syncthreads();
        int half = mc >> 1;
        int jb = w ? half : 0;
        int je = w ? mc : half;
        int j = jb;
        for (; j + 4 <= je; j += 4) {
            EDGE_LOAD(0, j)
            EDGE_LOAD(1, j + 1)
            EDGE_LOAD(2, j + 2)
            EDGE_LOAD(3, j + 3)
            EDGE_PROC(0)
            EDGE_PROC(1)
            EDGE_PROC(2)
            EDGE_PROC(3)
        }
        for (; j < je; ++j) {
            EDGE_LOAD(0, j)
            EDGE_PROC(0)
        }
        __syncthreads();
    }

    // merge the two waves' partials
    float* lw = &lsum[w][l * 8];
    lw[0] = acc0v[0]; lw[1] = acc0v[1]; lw[2] = acc1v[0]; lw[3] = acc1v[1];
    lw[4] = acc2v[0]; lw[5] = acc2v[1]; lw[6] = acc3v[0]; lw[7] = acc3v[1];
    if ((l & 15) == 0) ssum_s[w][hh] = ss;
    __syncthreads();
    if (t < 4) {
        float s = ssum_s[0][t] + ssum_s[1][t];
        inv_s[t] = (s > 0.f) ? 1.f / s : 0.f;
    }
    __syncthreads();

    int c = t;
    float o = 0.f;
    #pragma unroll
    for (int h = 0; h < 4; ++h)
        o = fmaf(lsum[0][h * 128 + c] + lsum[1][h * 128 + c], inv_s[h], o);
    o = o * 0.25f + b_out[c];
    float ge = 0.5f * o * (1.f + erff(o * 0.70710678118654752f));
    float y = h_in[(size_t)i * DM + c] + ge;

    float a = y, b = y * y;
    int lane = t & 63, wid = t >> 6;
    #pragma unroll
    for (int d = 1; d < 64; d <<= 1) {
        a += __shfl_xor(a, d, 64);
        b += __shfl_xor(b, d, 64);
    }
    if (lane == 0) { red[wid * 2 + 0] = a; red[wid * 2 + 1] = b; }
    __syncthreads();
    float mean = (red[0] + red[2]) * (1.f / 128.f);
    float var = (red[1] + red[3]) * (1.f / 128.f) - mean * mean;
    float rs = rsqrtf(var + 1e-5f);
    float out = (y - mean) * rs * ln_g[c] + ln_b[c];
    h_out[(size_t)i * DM + c] = out;
    hb_out[(size_t)i * DM + c] = f2b(out);
}

// ---------------- launch ----------------
extern "C" void kernel_launch(void* const* d_in, const int* in_sizes, int n_in,
                              void* d_out, int out_size, void* d_ws, size_t ws_size,
                              hipStream_t stream) {
    const float* x_flat   = (const float*)d_in[0];
    const int*   edge_idx = (const int*)d_in[1];
    const int*   edge_ty  = (const int*)d_in[2];
    const float* rel_emb  = (const float*)d_in[3];
    const float* Wl       = (const float*)d_in[4];
    const float* bl       = (const float*)d_in[5];
    const float* Wr       = (const float*)d_in[6];
    const float* br       = (const float*)d_in[7];
    const float* We       = (const float*)d_in[8];
    const float* att      = (const float*)d_in[9];
    const float* b_out    = (const float*)d_in[10];
    const float* ln_g     = (const float*)d_in[11];
    const float* ln_b     = (const float*)d_in[12];

    char* p = (char*)d_ws;
    auto carve = [&](size_t bytes) {
        void* r = (void*)p;
        p += (bytes + 255) & ~(size_t)255;
        return r;
    };
    unsigned short* xl     = (unsigned short*)carve((size_t)NN * HDIM * 2);
    unsigned short* xr     = (unsigned short*)carve((size_t)NN * HDIM * 2);
    float*          h1     = (float*)carve((size_t)NN * DM * 4);
    unsigned short* hb     = (unsigned short*)carve((size_t)NN * DM * 2);
    unsigned short* Wt     = (unsigned short*)carve((size_t)4 * DM * HDIM * 2);
    float*          xef    = (float*)carve((size_t)LAYERS * NRELS * HDIM * 4);
    float*          ab     = (float*)carve((size_t)NN * 8 * 4);
    float*          be     = (float*)carve((size_t)LAYERS * NRELS * NH * 4);
    int*            row_ptr= (int*)carve((size_t)(NN + 1) * 4);
    int*            counts = (int*)carve((size_t)NN * 4);
    int*            cursor = (int*)carve((size_t)NN * 4);
    int*            perm   = (int*)carve((size_t)EE * 4);
    int*            psums  = (int*)carve((size_t)NB * 4);
    int*            offs   = (int*)carve((size_t)NB * 4);

    const int* dst = edge_idx + EE;

    // CSR build (parallel scan)
    hipMemsetAsync(counts, 0, (size_t)NN * 4, stream);
    count_kernel<<<(EE + 255) / 256, 256, 0, stream>>>(dst, counts);
    psum_kernel<<<NB, 256, 0, stream>>>(counts, psums);
    pscan_kernel<<<1, 256, 0, stream>>>(psums, offs, row_ptr);
    pfin_kernel<<<NB, 256, 0, stream>>>(counts, offs, row_ptr, cursor);
    scatter_kernel<<<(EE + 255) / 256, 256, 0, stream>>>(dst, cursor, perm);

    // weight prep
    wconv_all_kernel<<<(4 * DM * HDIM + 255) / 256, 256, 0, stream>>>(Wl, Wr, Wt);
    xe_kernel<<<(LAYERS * NRELS * HDIM + 255) / 256, 256, 0, stream>>>(rel_emb, We, xef);
    be_kernel<<<(LAYERS * NRELS * NH + 255) / 256, 256, 0, stream>>>(xef, att, be);
    hb_kernel<<<(NN * DM / 4 + 255) / 256, 256, 0, stream>>>(x_flat, hb, NN * DM / 4);

    const float* h_cur = x_flat;
    for (int l = 0; l < LAYERS; ++l) {
        float* h_next = (l == LAYERS - 1) ? (float*)d_out : h1;
        gemm_xlxr_ab_kernel<<<(NN + 31) / 32, 256, 0, stream>>>(
            hb,
            Wt + (size_t)(l * 2 + 0) * DM * HDIM,
            Wt + (size_t)(l * 2 + 1) * DM * HDIM,
            bl + (size_t)l * HDIM, br + (size_t)l * HDIM,
            att + (size_t)l * HDIM,
            xl, xr, ab);
        node_fused_kernel<<<NN, 128, 0, stream>>>(
            row_ptr, perm, edge_idx, edge_ty, xl, xr,
            xef + (size_t)l * NRELS * HDIM,
            ab, be + (size_t)l * NRELS * NH,
            att + (size_t)l * HDIM,
            h_cur,
            b_out + (size_t)l * DM, ln_g + (size_t)l * DM, ln_b + (size_t)l * DM,
            h_next, hb);
        h_cur = h_next;
    }
}

// Round 7
// 626.970 us; speedup vs baseline: 1.8954x; 1.0226x over previous
//
#include <hip/hip_runtime.h>
#include <hip/hip_bf16.h>

#define NN 50000
#define DM 128
#define EE 800000
#define NH 4
#define HDIM 512      // NH * DM
#define NRELS 64
#define RDIM 64
#define LAYERS 2
#define NB 196        // ceil(NN/256)

typedef short frag8 __attribute__((ext_vector_type(8)));   // 8 bf16 (bits)
typedef float f32x4 __attribute__((ext_vector_type(4)));
typedef float f32x2 __attribute__((ext_vector_type(2)));

__device__ __forceinline__ float b2f(unsigned short u) {
    unsigned v = ((unsigned)u) << 16;
    union { unsigned u; float f; } c; c.u = v; return c.f;
}
__device__ __forceinline__ float b2f_lo(unsigned u) {
    union { unsigned u; float f; } c; c.u = u << 16; return c.f;
}
__device__ __forceinline__ float b2f_hi(unsigned u) {
    union { unsigned u; float f; } c; c.u = u & 0xFFFF0000u; return c.f;
}
__device__ __forceinline__ unsigned short f2b(float f) {
    union { float f; unsigned u; } c; c.f = f;
    unsigned u = c.u;
    u += 0x7FFFu + ((u >> 16) & 1u);   // round-to-nearest-even
    return (unsigned short)(u >> 16);
}

// ---------------- CSR build ----------------
__global__ void count_kernel(const int* __restrict__ dst, int* __restrict__ counts) {
    int e = blockIdx.x * 256 + threadIdx.x;
    if (e < EE) atomicAdd(&counts[dst[e]], 1);
}

__global__ __launch_bounds__(256) void psum_kernel(const int* __restrict__ counts,
                                                   int* __restrict__ psums) {
    int idx = blockIdx.x * 256 + threadIdx.x;
    int x = (idx < NN) ? counts[idx] : 0;
    int lane = threadIdx.x & 63, wv = threadIdx.x >> 6;
    #pragma unroll
    for (int d = 1; d < 64; d <<= 1) x += __shfl_xor(x, d, 64);
    __shared__ int ws[4];
    if (lane == 0) ws[wv] = x;
    __syncthreads();
    if (threadIdx.x == 0) psums[blockIdx.x] = ws[0] + ws[1] + ws[2] + ws[3];
}

__global__ __launch_bounds__(256) void pscan_kernel(const int* __restrict__ psums,
                                                    int* __restrict__ offs,
                                                    int* __restrict__ row_ptr) {
    int t = threadIdx.x;
    int x = (t < NB) ? psums[t] : 0;
    int lane = t & 63, wv = t >> 6;
    int incl = x;
    #pragma unroll
    for (int d = 1; d < 64; d <<= 1) {
        int y = __shfl_up(incl, d, 64);
        if (lane >= d) incl += y;
    }
    __shared__ int ws[4];
    if (lane == 63) ws[wv] = incl;
    __syncthreads();
    int off = 0;
    for (int k = 0; k < wv; ++k) off += ws[k];
    if (t < NB) offs[t] = incl + off - x;   // exclusive
    if (t == 0) row_ptr[0] = 0;
}

__global__ __launch_bounds__(256) void pfin_kernel(const int* __restrict__ counts,
                                                   const int* __restrict__ offs,
                                                   int* __restrict__ row_ptr,
                                                   int* __restrict__ cursor) {
    int idx = blockIdx.x * 256 + threadIdx.x;
    int x = (idx < NN) ? counts[idx] : 0;
    int lane = threadIdx.x & 63, wv = threadIdx.x >> 6;
    int incl = x;
    #pragma unroll
    for (int d = 1; d < 64; d <<= 1) {
        int y = __shfl_up(incl, d, 64);
        if (lane >= d) incl += y;
    }
    __shared__ int ws[4];
    if (lane == 63) ws[wv] = incl;
    __syncthreads();
    int off = offs[blockIdx.x];
    for (int k = 0; k < wv; ++k) off += ws[k];
    if (idx < NN) {
        int v = off + incl;
        row_ptr[idx + 1] = v;
        cursor[idx] = v - x;
    }
}

__global__ void scatter_kernel(const int* __restrict__ dst, int* __restrict__ cursor,
                               int* __restrict__ perm) {
    int e = blockIdx.x * 256 + threadIdx.x;
    if (e < EE) {
        int p = atomicAdd(&cursor[dst[e]], 1);
        perm[p] = e;
    }
}

// ---------------- prep kernels ----------------
__global__ void wconv_all_kernel(const float* __restrict__ Wl, const float* __restrict__ Wr,
                                 unsigned short* __restrict__ Wt) {
    int idx = blockIdx.x * 256 + threadIdx.x;
    if (idx >= 4 * DM * HDIM) return;
    int m = idx >> 16;          // 65536 elems per matrix
    int r = idx & 65535;
    int c = r >> 7, k = r & 127;
    int l = m >> 1;
    const float* W = (m & 1) ? Wr : Wl;
    Wt[idx] = f2b(W[(size_t)l * DM * HDIM + k * HDIM + c]);
}

__global__ void hb_kernel(const float* __restrict__ h, unsigned short* __restrict__ hb, int n4) {
    int idx = blockIdx.x * 256 + threadIdx.x;
    if (idx >= n4) return;
    float4 v = ((const float4*)h)[idx];
    ushort4 o;
    o.x = f2b(v.x); o.y = f2b(v.y); o.z = f2b(v.z); o.w = f2b(v.w);
    ((ushort4*)hb)[idx] = o;
}

// writes f32 table (for be) and bf16 table (for node kernel)
__global__ void xe_kernel(const float* __restrict__ rel_emb,  // [64][64]
                          const float* __restrict__ We,        // [2][64][512]
                          float* __restrict__ xef,             // [2][64][512] f32
                          unsigned short* __restrict__ xeb) {  // [2][64][512] bf16
    int idx = blockIdx.x * 256 + threadIdx.x;
    if (idx >= LAYERS * NRELS * HDIM) return;
    int l  = idx / (NRELS * HDIM);
    int r  = (idx / HDIM) & (NRELS - 1);
    int hc = idx & (HDIM - 1);
    const float* Wel = We + (size_t)l * RDIM * HDIM;
    float s = 0.f;
    #pragma unroll 8
    for (int d = 0; d < RDIM; ++d) s += rel_emb[r * RDIM + d] * Wel[d * HDIM + hc];
    xef[idx] = s;
    xeb[idx] = f2b(s);
}

// be[l][r][h] = 0.6 * sum_c att[l][h][c] * xe[l][r][h*128+c]
__global__ void be_kernel(const float* __restrict__ xef, const float* __restrict__ att,
                          float* __restrict__ be) {
    int tid = blockIdx.x * 256 + threadIdx.x;
    if (tid >= LAYERS * NRELS * NH) return;
    int l = tid >> 8;
    int r = (tid >> 2) & 63;
    int hh = tid & 3;
    const float* xp = xef + (size_t)l * NRELS * HDIM + r * HDIM + hh * DM;
    const float* ap = att + (size_t)l * HDIM + hh * DM;
    float s = 0.f;
    #pragma unroll 8
    for (int c = 0; c < DM; ++c) s += ap[c] * xp[c];
    be[tid] = 0.6f * s;
}

// per-edge (CSR order): cle[q] = 0.6 att.xl[src] + be[rel] (per head), pk[q] = (src<<6)|rel
__global__ void edge_prep_kernel(const int* __restrict__ perm, const int* __restrict__ ei,
                                 const int* __restrict__ etype,
                                 const float* __restrict__ ab, const float* __restrict__ be_l,
                                 float* __restrict__ cle, unsigned* __restrict__ pkq) {
    int q = blockIdx.x * 256 + threadIdx.x;
    if (q >= EE) return;
    int e = perm[q];
    int s = ei[e];
    int r = etype[e];
    float4 a4 = ((const float4*)ab)[2 * s];
    float4 b4 = ((const float4*)be_l)[r];
    float4 o;
    o.x = a4.x + b4.x; o.y = a4.y + b4.y; o.z = a4.z + b4.z; o.w = a4.w + b4.w;
    ((float4*)cle)[q] = o;
    pkq[q] = ((unsigned)s << 6) | (unsigned)r;
}

// ---------------- GEMM (M=32 tile) + fused ab ----------------
__global__ __launch_bounds__(256) void gemm_xlxr_ab_kernel(
    const unsigned short* __restrict__ hb,        // [NN,128] bf16
    const unsigned short* __restrict__ WtL,       // [512][128] bf16 (transposed)
    const unsigned short* __restrict__ WtR,
    const float* __restrict__ bl, const float* __restrict__ br,
    const float* __restrict__ att_l,              // [512]
    unsigned short* __restrict__ xl, unsigned short* __restrict__ xr,
    float* __restrict__ ab) {
    int w = threadIdx.x >> 6, lane = threadIdx.x & 63;   // wave w owns head w
    int m0 = blockIdx.x * 32;
    int colL = lane & 15, kg = lane >> 4;

    frag8 a[2][4];
    #pragma unroll
    for (int mt = 0; mt < 2; ++mt) {
        int row = m0 + mt * 16 + colL;
        if (row >= NN) row = NN - 1;
        const unsigned short* arow = hb + (size_t)row * DM;
        #pragma unroll
        for (int kc = 0; kc < 4; ++kc) {
            uint4 raw = *(const uint4*)(arow + kc * 32 + kg * 8);
            a[mt][kc] = __builtin_bit_cast(frag8, raw);
        }
    }

    float prow[2][2][4];   // [mt][mat][r]
    #pragma unroll
    for (int mt = 0; mt < 2; ++mt)
        #pragma unroll
        for (int mat = 0; mat < 2; ++mat)
            #pragma unroll
            for (int r = 0; r < 4; ++r) prow[mt][mat][r] = 0.f;

    #pragma unroll
    for (int mat = 0; mat < 2; ++mat) {
        const unsigned short* Wt = mat ? WtR : WtL;
        const float* bias = mat ? br : bl;
        unsigned short* out = mat ? xr : xl;
        #pragma unroll
        for (int nt = 0; nt < 8; ++nt) {
            int col = w * 128 + nt * 16 + colL;
            f32x4 acc0 = {0.f, 0.f, 0.f, 0.f};
            f32x4 acc1 = {0.f, 0.f, 0.f, 0.f};
            #pragma unroll
            for (int kc = 0; kc < 4; ++kc) {
                uint4 raw = *(const uint4*)(Wt + (size_t)col * DM + kc * 32 + kg * 8);
                frag8 b = __builtin_bit_cast(frag8, raw);
                acc0 = __builtin_amdgcn_mfma_f32_16x16x32_bf16(a[0][kc], b, acc0, 0, 0, 0);
                acc1 = __builtin_amdgcn_mfma_f32_16x16x32_bf16(a[1][kc], b, acc1, 0, 0, 0);
            }
            float bb = bias[col];
            float ac = att_l[col];
            #pragma unroll
            for (int r = 0; r < 4; ++r) {
                float v0 = acc0[r] + bb;
                float v1 = acc1[r] + bb;
                int row0 = m0 + kg * 4 + r;
                int row1 = row0 + 16;
                if (row0 < NN) out[(size_t)row0 * HDIM + col] = f2b(v0);
                if (row1 < NN) out[(size_t)row1 * HDIM + col] = f2b(v1);
                prow[0][mat][r] = fmaf(ac, v0, prow[0][mat][r]);
                prow[1][mat][r] = fmaf(ac, v1, prow[1][mat][r]);
            }
        }
    }
    #pragma unroll
    for (int d = 1; d < 16; d <<= 1) {
        #pragma unroll
        for (int mt = 0; mt < 2; ++mt)
            #pragma unroll
            for (int mat = 0; mat < 2; ++mat)
                #pragma unroll
                for (int r = 0; r < 4; ++r)
                    prow[mt][mat][r] += __shfl_xor(prow[mt][mat][r], d, 64);
    }
    if (colL == 0) {
        #pragma unroll
        for (int mt = 0; mt < 2; ++mt) {
            int row = m0 + mt * 16 + kg * 4;
            #pragma unroll
            for (int mat = 0; mat < 2; ++mat)
                #pragma unroll
                for (int r = 0; r < 4; ++r)
                    if (row + r < NN)
                        ab[(size_t)(row + r) * 8 + mat * 4 + w] = 0.6f * prow[mt][mat][r];
        }
    }
}

// ------- fused per-node: one WAVE per node, 4 nodes/block, no barriers -------
// Lane l owns channels l*8..l*8+7 of 512; head hh = l>>4.
__global__ __launch_bounds__(256) void node_fused_kernel(
    const int* __restrict__ row_ptr,
    const float* __restrict__ cle,           // [EE][4] f32, CSR order
    const unsigned* __restrict__ pkq,        // [EE] packed (src<<6)|rel, CSR order
    const unsigned short* __restrict__ xl,   // [NN][512] bf16
    const unsigned short* __restrict__ xr,   // [NN][512] bf16
    const unsigned short* __restrict__ xeb_l,// [64][512] bf16 (this layer)
    const float* __restrict__ ab,            // [NN][8] f32 (dst part at +4)
    const float* __restrict__ att_l,         // [512] (this layer)
    const float* __restrict__ h_in,          // [NN][128]
    const float* __restrict__ b_out, const float* __restrict__ ln_g,
    const float* __restrict__ ln_b,
    float* __restrict__ h_out,
    unsigned short* __restrict__ hb_out) {
    int w = threadIdx.x >> 6, l = threadIdx.x & 63;
    int i = blockIdx.x * 4 + w;
    int hh = l >> 4;
    __shared__ float cl[4][64][4];

    int beg = row_ptr[i], end = row_ptr[i + 1];
    int c0 = (l & 15) * 8;

    uint4 xrv = *(const uint4*)(xr + (size_t)i * HDIM + l * 8);
    f32x2 xrp0 = f32x2{b2f_lo(xrv.x), b2f_hi(xrv.x)};
    f32x2 xrp1 = f32x2{b2f_lo(xrv.y), b2f_hi(xrv.y)};
    f32x2 xrp2 = f32x2{b2f_lo(xrv.z), b2f_hi(xrv.z)};
    f32x2 xrp3 = f32x2{b2f_lo(xrv.w), b2f_hi(xrv.w)};
    float4 at0 = ((const float4*)(att_l + l * 8))[0];
    float4 at1 = ((const float4*)(att_l + l * 8))[1];
    float atv[8] = {at0.x * 0.4f, at0.y * 0.4f, at0.z * 0.4f, at0.w * 0.4f,
                    at1.x * 0.4f, at1.y * 0.4f, at1.z * 0.4f, at1.w * 0.4f};
    float4 bxv = ((const float4*)ab)[2 * i + 1];   // 0.6 att.xr_i per head
    float4 hv0 = *(const float4*)(h_in + (size_t)i * DM + c0);      // early issue
    float4 hv1 = *(const float4*)(h_in + (size_t)i * DM + c0 + 4);

    const char* xl_b = (const char*)xl;
    const char* xe_b = (const char*)xeb_l;
    uint l16 = (uint)l << 4;

    float ss = 0.f;
    f32x2 acc0 = f32x2{0.f, 0.f}, acc1 = f32x2{0.f, 0.f};
    f32x2 acc2 = f32x2{0.f, 0.f}, acc3 = f32x2{0.f, 0.f};

    for (int cb = beg; cb < end; cb += 64) {
        int mc = min(64, end - cb);
        unsigned pkr = 0;
        if (l < mc) {
            float4 c4 = ((const float4*)cle)[cb + l];
            pkr = pkq[cb + l];
            cl[w][l][0] = c4.x + bxv.x;
            cl[w][l][1] = c4.y + bxv.y;
            cl[w][l][2] = c4.z + bxv.z;
            cl[w][l][3] = c4.w + bxv.w;
        }
        // 2-deep pipeline over edges (wave-synchronous, no barrier)
        unsigned pk0 = __shfl(pkr, 0, 64);
        uint4 vvP = *(const uint4*)(xl_b + ((pk0 >> 6) << 10) + l16);
        uint4 eeP = *(const uint4*)(xe_b + ((pk0 & 63u) << 10) + l16);
        float cjP = cl[w][0][hh];
        for (int j = 1; j <= mc; ++j) {
            uint4 vv = vvP; uint4 ee = eeP; float cj = cjP;
            if (j < mc) {
                unsigned pkj = __shfl(pkr, j, 64);
                vvP = *(const uint4*)(xl_b + ((pkj >> 6) << 10) + l16);
                eeP = *(const uint4*)(xe_b + ((pkj & 63u) << 10) + l16);
                cjP = cl[w][j][hh];
            }
            f32x2 xp0 = f32x2{b2f_lo(vv.x), b2f_hi(vv.x)};
            f32x2 xp1 = f32x2{b2f_lo(vv.y), b2f_hi(vv.y)};
            f32x2 xp2 = f32x2{b2f_lo(vv.z), b2f_hi(vv.z)};
            f32x2 xp3 = f32x2{b2f_lo(vv.w), b2f_hi(vv.w)};
            f32x2 z0 = (xp0 + xrp0) + f32x2{b2f_lo(ee.x), b2f_hi(ee.x)};
            f32x2 z1 = (xp1 + xrp1) + f32x2{b2f_lo(ee.y), b2f_hi(ee.y)};
            f32x2 z2 = (xp2 + xrp2) + f32x2{b2f_lo(ee.z), b2f_hi(ee.z)};
            f32x2 z3 = (xp3 + xrp3) + f32x2{b2f_lo(ee.w), b2f_hi(ee.w)};
            float partial = fmaf(atv[0], fabsf(z0[0]),
                            fmaf(atv[1], fabsf(z0[1]),
                            fmaf(atv[2], fabsf(z1[0]),
                            fmaf(atv[3], fabsf(z1[1]),
                            fmaf(atv[4], fabsf(z2[0]),
                            fmaf(atv[5], fabsf(z2[1]),
                            fmaf(atv[6], fabsf(z3[0]), atv[7] * fabsf(z3[1]))))))));
            #pragma unroll
            for (int d = 1; d < 16; d <<= 1) partial += __shfl_xor(partial, d, 64);
            float we = __expf(partial + cj);
            ss += we;
            f32x2 wv = f32x2{we, we};
            acc0 += wv * xp0;
            acc1 += wv * xp1;
            acc2 += wv * xp2;
            acc3 += wv * xp3;
        }
    }

    // normalize per head, then sum across the 4 head groups (lanes ^16, ^32)
    float invs = (ss > 0.f) ? 1.f / ss : 0.f;
    float sv[8] = {acc0[0] * invs, acc0[1] * invs, acc1[0] * invs, acc1[1] * invs,
                   acc2[0] * invs, acc2[1] * invs, acc3[0] * invs, acc3[1] * invs};
    #pragma unroll
    for (int d = 16; d < 64; d <<= 1)
        #pragma unroll
        for (int k = 0; k < 8; ++k) sv[k] += __shfl_xor(sv[k], d, 64);

    float4 bo0 = *(const float4*)(b_out + c0);
    float4 bo1 = *(const float4*)(b_out + c0 + 4);
    float bov[8] = {bo0.x, bo0.y, bo0.z, bo0.w, bo1.x, bo1.y, bo1.z, bo1.w};
    float hvv[8] = {hv0.x, hv0.y, hv0.z, hv0.w, hv1.x, hv1.y, hv1.z, hv1.w};
    float yv[8];
    float la = 0.f, lb = 0.f;
    #pragma unroll
    for (int k = 0; k < 8; ++k) {
        float o = sv[k] * 0.25f + bov[k];
        float ge = 0.5f * o * (1.f + erff(o * 0.70710678118654752f));
        float y = hvv[k] + ge;
        yv[k] = y; la += y; lb += y * y;
    }
    #pragma unroll
    for (int d = 1; d < 16; d <<= 1) {
        la += __shfl_xor(la, d, 64);
        lb += __shfl_xor(lb, d, 64);
    }
    float mean = la * (1.f / 128.f);
    float var = lb * (1.f / 128.f) - mean * mean;
    float rs = rsqrtf(var + 1e-5f);

    if (l < 16) {
        float4 g0 = *(const float4*)(ln_g + c0);
        float4 g1 = *(const float4*)(ln_g + c0 + 4);
        float4 q0 = *(const float4*)(ln_b + c0);
        float4 q1 = *(const float4*)(ln_b + c0 + 4);
        float gv[8] = {g0.x, g0.y, g0.z, g0.w, g1.x, g1.y, g1.z, g1.w};
        float qv[8] = {q0.x, q0.y, q0.z, q0.w, q1.x, q1.y, q1.z, q1.w};
        float ov[8];
        #pragma unroll
        for (int k = 0; k < 8; ++k)
            ov[k] = (yv[k] - mean) * rs * gv[k] + qv[k];
        float* hop = h_out + (size_t)i * DM + c0;
        *(float4*)hop = make_float4(ov[0], ov[1], ov[2], ov[3]);
        *(float4*)(hop + 4) = make_float4(ov[4], ov[5], ov[6], ov[7]);
        uint4 ob;
        ob.x = (unsigned)f2b(ov[0]) | ((unsigned)f2b(ov[1]) << 16);
        ob.y = (unsigned)f2b(ov[2]) | ((unsigned)f2b(ov[3]) << 16);
        ob.z = (unsigned)f2b(ov[4]) | ((unsigned)f2b(ov[5]) << 16);
        ob.w = (unsigned)f2b(ov[6]) | ((unsigned)f2b(ov[7]) << 16);
        *(uint4*)(hb_out + (size_t)i * DM + c0) = ob;
    }
}

// ---------------- launch ----------------
extern "C" void kernel_launch(void* const* d_in, const int* in_sizes, int n_in,
                              void* d_out, int out_size, void* d_ws, size_t ws_size,
                              hipStream_t stream) {
    const float* x_flat   = (const float*)d_in[0];
    const int*   edge_idx = (const int*)d_in[1];
    const int*   edge_ty  = (const int*)d_in[2];
    const float* rel_emb  = (const float*)d_in[3];
    const float* Wl       = (const float*)d_in[4];
    const float* bl       = (const float*)d_in[5];
    const float* Wr       = (const float*)d_in[6];
    const float* br       = (const float*)d_in[7];
    const float* We       = (const float*)d_in[8];
    const float* att      = (const float*)d_in[9];
    const float* b_out    = (const float*)d_in[10];
    const float* ln_g     = (const float*)d_in[11];
    const float* ln_b     = (const float*)d_in[12];

    char* p = (char*)d_ws;
    auto carve = [&](size_t bytes) {
        void* r = (void*)p;
        p += (bytes + 255) & ~(size_t)255;
        return r;
    };
    unsigned short* xl     = (unsigned short*)carve((size_t)NN * HDIM * 2);
    unsigned short* xr     = (unsigned short*)carve((size_t)NN * HDIM * 2);
    float*          h1     = (float*)carve((size_t)NN * DM * 4);
    unsigned short* hb     = (unsigned short*)carve((size_t)NN * DM * 2);
    unsigned short* Wt     = (unsigned short*)carve((size_t)4 * DM * HDIM * 2);
    float*          xef    = (float*)carve((size_t)LAYERS * NRELS * HDIM * 4);
    unsigned short* xeb    = (unsigned short*)carve((size_t)LAYERS * NRELS * HDIM * 2);
    float*          ab     = (float*)carve((size_t)NN * 8 * 4);
    float*          be     = (float*)carve((size_t)LAYERS * NRELS * NH * 4);
    int*            row_ptr= (int*)carve((size_t)(NN + 1) * 4);
    int*            counts = (int*)carve((size_t)NN * 4);
    int*            cursor = (int*)carve((size_t)NN * 4);
    int*            perm   = (int*)carve((size_t)EE * 4);
    int*            psums  = (int*)carve((size_t)NB * 4);
    int*            offs   = (int*)carve((size_t)NB * 4);
    float*          cle    = (float*)carve((size_t)EE * 4 * 4);
    unsigned*       pkq    = (unsigned*)carve((size_t)EE * 4);

    const int* dst = edge_idx + EE;

    // CSR build (parallel scan)
    hipMemsetAsync(counts, 0, (size_t)NN * 4, stream);
    count_kernel<<<(EE + 255) / 256, 256, 0, stream>>>(dst, counts);
    psum_kernel<<<NB, 256, 0, stream>>>(counts, psums);
    pscan_kernel<<<1, 256, 0, stream>>>(psums, offs, row_ptr);
    pfin_kernel<<<NB, 256, 0, stream>>>(counts, offs, row_ptr, cursor);
    scatter_kernel<<<(EE + 255) / 256, 256, 0, stream>>>(dst, cursor, perm);

    // weight prep
    wconv_all_kernel<<<(4 * DM * HDIM + 255) / 256, 256, 0, stream>>>(Wl, Wr, Wt);
    xe_kernel<<<(LAYERS * NRELS * HDIM + 255) / 256, 256, 0, stream>>>(rel_emb, We, xef, xeb);
    be_kernel<<<(LAYERS * NRELS * NH + 255) / 256, 256, 0, stream>>>(xef, att, be);
    hb_kernel<<<(NN * DM / 4 + 255) / 256, 256, 0, stream>>>(x_flat, hb, NN * DM / 4);

    const float* h_cur = x_flat;
    for (int l = 0; l < LAYERS; ++l) {
        float* h_next = (l == LAYERS - 1) ? (float*)d_out : h1;
        gemm_xlxr_ab_kernel<<<(NN + 31) / 32, 256, 0, stream>>>(
            hb,
            Wt + (size_t)(l * 2 + 0) * DM * HDIM,
            Wt + (size_t)(l * 2 + 1) * DM * HDIM,
            bl + (size_t)l * HDIM, br + (size_t)l * HDIM,
            att + (size_t)l * HDIM,
            xl, xr, ab);
        edge_prep_kernel<<<(EE + 255) / 256, 256, 0, stream>>>(
            perm, edge_idx, edge_ty, ab, be + (size_t)l * NRELS * NH, cle, pkq);
        node_fused_kernel<<<NN / 4, 256, 0, stream>>>(
            row_ptr, cle, pkq, xl, xr,
            xeb + (size_t)l * NRELS * HDIM,
            ab,
            att + (size_t)l * HDIM,
            h_cur,
            b_out + (size_t)l * DM, ln_g + (size_t)l * DM, ln_b + (size_t)l * DM,
            h_next, hb);
        h_cur = h_next;
    }
}

// Round 8
// 558.250 us; speedup vs baseline: 2.1287x; 1.1231x over previous
//
#include <hip/hip_runtime.h>
#include <hip/hip_bf16.h>

#define NN 50000
#define DM 128
#define EE 800000
#define NH 4
#define HDIM 512      // NH * DM
#define NRELS 64
#define RDIM 64
#define LAYERS 2
#define NB 196        // ceil(NN/256)

// prep_misc block ranges
#define PM_HB 6250    // NN*DM/4/256
#define PM_WC 1024    // 4*DM*HDIM/256
#define PM_XE 256     // LAYERS*NRELS*HDIM/256
#define PM_CZ 196     // NB
#define PM_TOT (PM_HB + PM_WC + PM_XE + PM_CZ + 1)

typedef short frag8 __attribute__((ext_vector_type(8)));   // 8 bf16 (bits)
typedef float f32x4 __attribute__((ext_vector_type(4)));
typedef float f32x2 __attribute__((ext_vector_type(2)));

__device__ __forceinline__ float b2f(unsigned short u) {
    unsigned v = ((unsigned)u) << 16;
    union { unsigned u; float f; } c; c.u = v; return c.f;
}
__device__ __forceinline__ float b2f_lo(unsigned u) {
    union { unsigned u; float f; } c; c.u = u << 16; return c.f;
}
__device__ __forceinline__ float b2f_hi(unsigned u) {
    union { unsigned u; float f; } c; c.u = u & 0xFFFF0000u; return c.f;
}
__device__ __forceinline__ unsigned short f2b(float f) {
    union { float f; unsigned u; } c; c.f = f;
    unsigned u = c.u;
    u += 0x7FFFu + ((u >> 16) & 1u);   // round-to-nearest-even
    return (unsigned short)(u >> 16);
}

// DPP 16-lane row sum-reduce step (pure VALU, no DS)
template<int CTRL>
__device__ __forceinline__ float dpp_add(float x) {
    int yi = __builtin_amdgcn_update_dpp(0, __builtin_bit_cast(int, x),
                                         CTRL, 0xF, 0xF, true);
    return x + __builtin_bit_cast(float, yi);
}

// ---------------- CSR build ----------------
__global__ void count_kernel(const int* __restrict__ dst, int* __restrict__ counts) {
    int e = blockIdx.x * 256 + threadIdx.x;
    if (e < EE) atomicAdd(&counts[dst[e]], 1);
}

__global__ __launch_bounds__(256) void psum_kernel(const int* __restrict__ counts,
                                                   int* __restrict__ psums) {
    int idx = blockIdx.x * 256 + threadIdx.x;
    int x = (idx < NN) ? counts[idx] : 0;
    int lane = threadIdx.x & 63, wv = threadIdx.x >> 6;
    #pragma unroll
    for (int d = 1; d < 64; d <<= 1) x += __shfl_xor(x, d, 64);
    __shared__ int ws[4];
    if (lane == 0) ws[wv] = x;
    __syncthreads();
    if (threadIdx.x == 0) psums[blockIdx.x] = ws[0] + ws[1] + ws[2] + ws[3];
}

__global__ __launch_bounds__(256) void pscan_kernel(const int* __restrict__ psums,
                                                    int* __restrict__ offs,
                                                    int* __restrict__ row_ptr) {
    int t = threadIdx.x;
    int x = (t < NB) ? psums[t] : 0;
    int lane = t & 63, wv = t >> 6;
    int incl = x;
    #pragma unroll
    for (int d = 1; d < 64; d <<= 1) {
        int y = __shfl_up(incl, d, 64);
        if (lane >= d) incl += y;
    }
    __shared__ int ws[4];
    if (lane == 63) ws[wv] = incl;
    __syncthreads();
    int off = 0;
    for (int k = 0; k < wv; ++k) off += ws[k];
    if (t < NB) offs[t] = incl + off - x;   // exclusive
    if (t == 0) row_ptr[0] = 0;
}

__global__ __launch_bounds__(256) void pfin_kernel(const int* __restrict__ counts,
                                                   const int* __restrict__ offs,
                                                   int* __restrict__ row_ptr,
                                                   int* __restrict__ cursor) {
    int idx = blockIdx.x * 256 + threadIdx.x;
    int x = (idx < NN) ? counts[idx] : 0;
    int lane = threadIdx.x & 63, wv = threadIdx.x >> 6;
    int incl = x;
    #pragma unroll
    for (int d = 1; d < 64; d <<= 1) {
        int y = __shfl_up(incl, d, 64);
        if (lane >= d) incl += y;
    }
    __shared__ int ws[4];
    if (lane == 63) ws[wv] = incl;
    __syncthreads();
    int off = offs[blockIdx.x];
    for (int k = 0; k < wv; ++k) off += ws[k];
    if (idx < NN) {
        int v = off + incl;
        row_ptr[idx + 1] = v;
        cursor[idx] = v - x;
    }
}

// scatter + pkq build (layer-invariant): pkq[p] = (src<<6)|rel in CSR order
__global__ void scatter_pk_kernel(const int* __restrict__ ei, const int* __restrict__ etype,
                                  int* __restrict__ cursor, unsigned* __restrict__ pkq) {
    int e = blockIdx.x * 256 + threadIdx.x;
    if (e < EE) {
        int d = ei[EE + e];
        int p = atomicAdd(&cursor[d], 1);
        pkq[p] = ((unsigned)ei[e] << 6) | (unsigned)etype[e];
    }
}

// ---------------- fused prep: hb, wconv, xe(bf16), counts=0, be ----------------
__global__ __launch_bounds__(256) void prep_misc_kernel(
    const float* __restrict__ x_flat,
    const float* __restrict__ Wl, const float* __restrict__ Wr,
    const float* __restrict__ rel_emb, const float* __restrict__ We,
    const float* __restrict__ att,
    unsigned short* __restrict__ hb, unsigned short* __restrict__ Wt,
    unsigned short* __restrict__ xeb, float* __restrict__ be,
    int* __restrict__ counts) {
    int b = blockIdx.x, t = threadIdx.x;
    if (b < PM_HB) {
        int idx = b * 256 + t;                      // < NN*DM/4
        float4 v = ((const float4*)x_flat)[idx];
        ushort4 o;
        o.x = f2b(v.x); o.y = f2b(v.y); o.z = f2b(v.z); o.w = f2b(v.w);
        ((ushort4*)hb)[idx] = o;
        return;
    }
    b -= PM_HB;
    if (b < PM_WC) {
        int idx = b * 256 + t;                      // < 4*DM*HDIM
        int m = idx >> 16;
        int r = idx & 65535;
        int c = r >> 7, k = r & 127;
        int l = m >> 1;
        const float* W = (m & 1) ? Wr : Wl;
        Wt[idx] = f2b(W[(size_t)l * DM * HDIM + k * HDIM + c]);
        return;
    }
    b -= PM_WC;
    if (b < PM_XE) {
        int idx = b * 256 + t;                      // < LAYERS*NRELS*HDIM
        int l  = idx / (NRELS * HDIM);
        int r  = (idx / HDIM) & (NRELS - 1);
        int hc = idx & (HDIM - 1);
        const float* Wel = We + (size_t)l * RDIM * HDIM;
        float s = 0.f;
        #pragma unroll 8
        for (int d = 0; d < RDIM; ++d) s += rel_emb[r * RDIM + d] * Wel[d * HDIM + hc];
        xeb[idx] = f2b(s);
        return;
    }
    b -= PM_XE;
    if (b < PM_CZ) {
        int idx = b * 256 + t;
        if (idx < NN) counts[idx] = 0;
        return;
    }
    // be block: aw[l][h][d] = sum_c att[l][h][c]*We[l][d][h*128+c];
    // be[l][r][h] = 0.6 * sum_d rel_emb[r][d]*aw[l][h][d]
    __shared__ float aw_s[LAYERS * NH * RDIM];      // 512
    #pragma unroll
    for (int k = 0; k < 2; ++k) {
        int idx = t * 2 + k;                        // < 512
        int l = idx >> 8, h = (idx >> 6) & 3, d = idx & 63;
        const float* ap = att + (size_t)l * HDIM + h * DM;
        const float* wp = We + (size_t)l * RDIM * HDIM + (size_t)d * HDIM + h * DM;
        float s = 0.f;
        #pragma unroll 8
        for (int c = 0; c < DM; ++c) s += ap[c] * wp[c];
        aw_s[idx] = s;
    }
    __syncthreads();
    #pragma unroll
    for (int k = 0; k < 2; ++k) {
        int idx = t * 2 + k;                        // < 512 = L*NRELS*NH
        int l = idx >> 8, r = (idx >> 2) & 63, h = idx & 3;
        const float* rp = rel_emb + r * RDIM;
        const float* ap = aw_s + l * 256 + h * 64;
        float s = 0.f;
        #pragma unroll 8
        for (int d = 0; d < RDIM; ++d) s += rp[d] * ap[d];
        be[idx] = 0.6f * s;
    }
}

// ---------------- GEMM (M=32 tile) + fused ab ----------------
__global__ __launch_bounds__(256) void gemm_xlxr_ab_kernel(
    const unsigned short* __restrict__ hb,        // [NN,128] bf16
    const unsigned short* __restrict__ WtL,       // [512][128] bf16 (transposed)
    const unsigned short* __restrict__ WtR,
    const float* __restrict__ bl, const float* __restrict__ br,
    const float* __restrict__ att_l,              // [512]
    unsigned short* __restrict__ xl, unsigned short* __restrict__ xr,
    float* __restrict__ ab) {
    int w = threadIdx.x >> 6, lane = threadIdx.x & 63;   // wave w owns head w
    int m0 = blockIdx.x * 32;
    int colL = lane & 15, kg = lane >> 4;

    frag8 a[2][4];
    #pragma unroll
    for (int mt = 0; mt < 2; ++mt) {
        int row = m0 + mt * 16 + colL;
        if (row >= NN) row = NN - 1;
        const unsigned short* arow = hb + (size_t)row * DM;
        #pragma unroll
        for (int kc = 0; kc < 4; ++kc) {
            uint4 raw = *(const uint4*)(arow + kc * 32 + kg * 8);
            a[mt][kc] = __builtin_bit_cast(frag8, raw);
        }
    }

    float prow[2][2][4];   // [mt][mat][r]
    #pragma unroll
    for (int mt = 0; mt < 2; ++mt)
        #pragma unroll
        for (int mat = 0; mat < 2; ++mat)
            #pragma unroll
            for (int r = 0; r < 4; ++r) prow[mt][mat][r] = 0.f;

    #pragma unroll
    for (int mat = 0; mat < 2; ++mat) {
        const unsigned short* Wt = mat ? WtR : WtL;
        const float* bias = mat ? br : bl;
        unsigned short* out = mat ? xr : xl;
        #pragma unroll
        for (int nt = 0; nt < 8; ++nt) {
            int col = w * 128 + nt * 16 + colL;
            f32x4 acc0 = {0.f, 0.f, 0.f, 0.f};
            f32x4 acc1 = {0.f, 0.f, 0.f, 0.f};
            #pragma unroll
            for (int kc = 0; kc < 4; ++kc) {
                uint4 raw = *(const uint4*)(Wt + (size_t)col * DM + kc * 32 + kg * 8);
                frag8 b = __builtin_bit_cast(frag8, raw);
                acc0 = __builtin_amdgcn_mfma_f32_16x16x32_bf16(a[0][kc], b, acc0, 0, 0, 0);
                acc1 = __builtin_amdgcn_mfma_f32_16x16x32_bf16(a[1][kc], b, acc1, 0, 0, 0);
            }
            float bb = bias[col];
            float ac = att_l[col];
            #pragma unroll
            for (int r = 0; r < 4; ++r) {
                float v0 = acc0[r] + bb;
                float v1 = acc1[r] + bb;
                int row0 = m0 + kg * 4 + r;
                int row1 = row0 + 16;
                if (row0 < NN) out[(size_t)row0 * HDIM + col] = f2b(v0);
                if (row1 < NN) out[(size_t)row1 * HDIM + col] = f2b(v1);
                prow[0][mat][r] = fmaf(ac, v0, prow[0][mat][r]);
                prow[1][mat][r] = fmaf(ac, v1, prow[1][mat][r]);
            }
        }
    }
    #pragma unroll
    for (int d = 1; d < 16; d <<= 1) {
        #pragma unroll
        for (int mt = 0; mt < 2; ++mt)
            #pragma unroll
            for (int mat = 0; mat < 2; ++mat)
                #pragma unroll
                for (int r = 0; r < 4; ++r)
                    prow[mt][mat][r] += __shfl_xor(prow[mt][mat][r], d, 64);
    }
    if (colL == 0) {
        #pragma unroll
        for (int mt = 0; mt < 2; ++mt) {
            int row = m0 + mt * 16 + kg * 4;
            #pragma unroll
            for (int mat = 0; mat < 2; ++mat)
                #pragma unroll
                for (int r = 0; r < 4; ++r)
                    if (row + r < NN)
                        ab[(size_t)(row + r) * 8 + mat * 4 + w] = 0.6f * prow[mt][mat][r];
        }
    }
}

// ------- fused per-node: one WAVE per node, 4 nodes/block, no barriers, DPP reduce -------
__global__ __launch_bounds__(256) void node_fused_kernel(
    const int* __restrict__ row_ptr,
    const unsigned* __restrict__ pkq,        // [EE] packed (src<<6)|rel, CSR order
    const unsigned short* __restrict__ xl,   // [NN][512] bf16
    const unsigned short* __restrict__ xr,   // [NN][512] bf16
    const unsigned short* __restrict__ xeb_l,// [64][512] bf16 (this layer)
    const float* __restrict__ ab,            // [NN][8] f32 (dst part at +4)
    const float* __restrict__ be_l,          // [64][4] f32 (this layer)
    const float* __restrict__ att_l,         // [512] (this layer)
    const float* __restrict__ h_in,          // [NN][128]
    const float* __restrict__ b_out, const float* __restrict__ ln_g,
    const float* __restrict__ ln_b,
    float* __restrict__ h_out,
    unsigned short* __restrict__ hb_out) {
    int w = threadIdx.x >> 6, l = threadIdx.x & 63;
    int i = blockIdx.x * 4 + w;
    int hh = l >> 4;
    __shared__ float cl[4][64][4];
    __shared__ unsigned pk_s[4][64];

    int beg = row_ptr[i], end = row_ptr[i + 1];
    int c0 = (l & 15) * 8;

    uint4 xrv = *(const uint4*)(xr + (size_t)i * HDIM + l * 8);
    f32x2 xrp0 = f32x2{b2f_lo(xrv.x), b2f_hi(xrv.x)};
    f32x2 xrp1 = f32x2{b2f_lo(xrv.y), b2f_hi(xrv.y)};
    f32x2 xrp2 = f32x2{b2f_lo(xrv.z), b2f_hi(xrv.z)};
    f32x2 xrp3 = f32x2{b2f_lo(xrv.w), b2f_hi(xrv.w)};
    float4 at0 = ((const float4*)(att_l + l * 8))[0];
    float4 at1 = ((const float4*)(att_l + l * 8))[1];
    float atv[8] = {at0.x * 0.4f, at0.y * 0.4f, at0.z * 0.4f, at0.w * 0.4f,
                    at1.x * 0.4f, at1.y * 0.4f, at1.z * 0.4f, at1.w * 0.4f};
    float4 bxv = ((const float4*)ab)[2 * i + 1];   // 0.6 att.xr_i per head
    float4 hv0 = *(const float4*)(h_in + (size_t)i * DM + c0);      // early issue
    float4 hv1 = *(const float4*)(h_in + (size_t)i * DM + c0 + 4);

    const char* xl_b = (const char*)xl;
    const char* xe_b = (const char*)xeb_l;
    uint l16 = (uint)l << 4;

    float ss = 0.f;
    f32x2 acc0 = f32x2{0.f, 0.f}, acc1 = f32x2{0.f, 0.f};
    f32x2 acc2 = f32x2{0.f, 0.f}, acc3 = f32x2{0.f, 0.f};

    for (int cb = beg; cb < end; cb += 64) {
        int mc = min(64, end - cb);
        if (l < mc) {
            unsigned pk = pkq[cb + l];
            pk_s[w][l] = pk;
            int s = pk >> 6, r = pk & 63;
            float4 a4 = ((const float4*)ab)[2 * s];
            float4 b4 = ((const float4*)be_l)[r];
            cl[w][l][0] = a4.x + b4.x + bxv.x;
            cl[w][l][1] = a4.y + b4.y + bxv.y;
            cl[w][l][2] = a4.z + b4.z + bxv.z;
            cl[w][l][3] = a4.w + b4.w + bxv.w;
        }
        // 2-deep pipeline over edges (wave-synchronous, no barrier)
        unsigned pk0 = pk_s[w][0];
        uint4 vvP = *(const uint4*)(xl_b + ((pk0 >> 6) << 10) + l16);
        uint4 eeP = *(const uint4*)(xe_b + ((pk0 & 63u) << 10) + l16);
        float cjP = cl[w][0][hh];
        for (int j = 1; j <= mc; ++j) {
            uint4 vv = vvP; uint4 ee = eeP; float cj = cjP;
            if (j < mc) {
                unsigned pkj = pk_s[w][j];
                vvP = *(const uint4*)(xl_b + ((pkj >> 6) << 10) + l16);
                eeP = *(const uint4*)(xe_b + ((pkj & 63u) << 10) + l16);
                cjP = cl[w][j][hh];
            }
            f32x2 xp0 = f32x2{b2f_lo(vv.x), b2f_hi(vv.x)};
            f32x2 xp1 = f32x2{b2f_lo(vv.y), b2f_hi(vv.y)};
            f32x2 xp2 = f32x2{b2f_lo(vv.z), b2f_hi(vv.z)};
            f32x2 xp3 = f32x2{b2f_lo(vv.w), b2f_hi(vv.w)};
            f32x2 z0 = (xp0 + xrp0) + f32x2{b2f_lo(ee.x), b2f_hi(ee.x)};
            f32x2 z1 = (xp1 + xrp1) + f32x2{b2f_lo(ee.y), b2f_hi(ee.y)};
            f32x2 z2 = (xp2 + xrp2) + f32x2{b2f_lo(ee.z), b2f_hi(ee.z)};
            f32x2 z3 = (xp3 + xrp3) + f32x2{b2f_lo(ee.w), b2f_hi(ee.w)};
            float partial = fmaf(atv[0], fabsf(z0[0]),
                            fmaf(atv[1], fabsf(z0[1]),
                            fmaf(atv[2], fabsf(z1[0]),
                            fmaf(atv[3], fabsf(z1[1]),
                            fmaf(atv[4], fabsf(z2[0]),
                            fmaf(atv[5], fabsf(z2[1]),
                            fmaf(atv[6], fabsf(z3[0]), atv[7] * fabsf(z3[1]))))))));
            // 16-lane row reduce via DPP (xor1, xor2, ror4, ror8) — pure VALU
            partial = dpp_add<0xB1>(partial);
            partial = dpp_add<0x4E>(partial);
            partial = dpp_add<0x124>(partial);
            partial = dpp_add<0x128>(partial);
            float we = __expf(partial + cj);
            ss += we;
            f32x2 wv = f32x2{we, we};
            acc0 += wv * xp0;
            acc1 += wv * xp1;
            acc2 += wv * xp2;
            acc3 += wv * xp3;
        }
    }

    // normalize per head, then sum across the 4 head groups (lanes ^16, ^32)
    float invs = (ss > 0.f) ? 1.f / ss : 0.f;
    float sv[8] = {acc0[0] * invs, acc0[1] * invs, acc1[0] * invs, acc1[1] * invs,
                   acc2[0] * invs, acc2[1] * invs, acc3[0] * invs, acc3[1] * invs};
    #pragma unroll
    for (int d = 16; d < 64; d <<= 1)
        #pragma unroll
        for (int k = 0; k < 8; ++k) sv[k] += __shfl_xor(sv[k], d, 64);

    float4 bo0 = *(const float4*)(b_out + c0);
    float4 bo1 = *(const float4*)(b_out + c0 + 4);
    float bov[8] = {bo0.x, bo0.y, bo0.z, bo0.w, bo1.x, bo1.y, bo1.z, bo1.w};
    float hvv[8] = {hv0.x, hv0.y, hv0.z, hv0.w, hv1.x, hv1.y, hv1.z, hv1.w};
    float yv[8];
    float la = 0.f, lb = 0.f;
    #pragma unroll
    for (int k = 0; k < 8; ++k) {
        float o = sv[k] * 0.25f + bov[k];
        float ge = 0.5f * o * (1.f + erff(o * 0.70710678118654752f));
        float y = hvv[k] + ge;
        yv[k] = y; la += y; lb += y * y;
    }
    // sum within the 16-lane row (each row holds the full 128 channels)
    la = dpp_add<0xB1>(la); la = dpp_add<0x4E>(la);
    la = dpp_add<0x124>(la); la = dpp_add<0x128>(la);
    lb = dpp_add<0xB1>(lb); lb = dpp_add<0x4E>(lb);
    lb = dpp_add<0x124>(lb); lb = dpp_add<0x128>(lb);
    float mean = la * (1.f / 128.f);
    float var = lb * (1.f / 128.f) - mean * mean;
    float rs = rsqrtf(var + 1e-5f);

    if (l < 16) {
        float4 g0 = *(const float4*)(ln_g + c0);
        float4 g1 = *(const float4*)(ln_g + c0 + 4);
        float4 q0 = *(const float4*)(ln_b + c0);
        float4 q1 = *(const float4*)(ln_b + c0 + 4);
        float gv[8] = {g0.x, g0.y, g0.z, g0.w, g1.x, g1.y, g1.z, g1.w};
        float qv[8] = {q0.x, q0.y, q0.z, q0.w, q1.x, q1.y, q1.z, q1.w};
        float ov[8];
        #pragma unroll
        for (int k = 0; k < 8; ++k)
            ov[k] = (yv[k] - mean) * rs * gv[k] + qv[k];
        float* hop = h_out + (size_t)i * DM + c0;
        *(float4*)hop = make_float4(ov[0], ov[1], ov[2], ov[3]);
        *(float4*)(hop + 4) = make_float4(ov[4], ov[5], ov[6], ov[7]);
        uint4 ob;
        ob.x = (unsigned)f2b(ov[0]) | ((unsigned)f2b(ov[1]) << 16);
        ob.y = (unsigned)f2b(ov[2]) | ((unsigned)f2b(ov[3]) << 16);
        ob.z = (unsigned)f2b(ov[4]) | ((unsigned)f2b(ov[5]) << 16);
        ob.w = (unsigned)f2b(ov[6]) | ((unsigned)f2b(ov[7]) << 16);
        *(uint4*)(hb_out + (size_t)i * DM + c0) = ob;
    }
}

// ---------------- launch ----------------
extern "C" void kernel_launch(void* const* d_in, const int* in_sizes, int n_in,
                              void* d_out, int out_size, void* d_ws, size_t ws_size,
                              hipStream_t stream) {
    const float* x_flat   = (const float*)d_in[0];
    const int*   edge_idx = (const int*)d_in[1];
    const int*   edge_ty  = (const int*)d_in[2];
    const float* rel_emb  = (const float*)d_in[3];
    const float* Wl       = (const float*)d_in[4];
    const float* bl       = (const float*)d_in[5];
    const float* Wr       = (const float*)d_in[6];
    const float* br       = (const float*)d_in[7];
    const float* We       = (const float*)d_in[8];
    const float* att      = (const float*)d_in[9];
    const float* b_out    = (const float*)d_in[10];
    const float* ln_g     = (const float*)d_in[11];
    const float* ln_b     = (const float*)d_in[12];

    char* p = (char*)d_ws;
    auto carve = [&](size_t bytes) {
        void* r = (void*)p;
        p += (bytes + 255) & ~(size_t)255;
        return r;
    };
    unsigned short* xl     = (unsigned short*)carve((size_t)NN * HDIM * 2);
    unsigned short* xr     = (unsigned short*)carve((size_t)NN * HDIM * 2);
    float*          h1     = (float*)carve((size_t)NN * DM * 4);
    unsigned short* hb     = (unsigned short*)carve((size_t)NN * DM * 2);
    unsigned short* Wt     = (unsigned short*)carve((size_t)4 * DM * HDIM * 2);
    unsigned short* xeb    = (unsigned short*)carve((size_t)LAYERS * NRELS * HDIM * 2);
    float*          ab     = (float*)carve((size_t)NN * 8 * 4);
    float*          be     = (float*)carve((size_t)LAYERS * NRELS * NH * 4);
    int*            row_ptr= (int*)carve((size_t)(NN + 1) * 4);
    int*            counts = (int*)carve((size_t)NN * 4);
    int*            cursor = (int*)carve((size_t)NN * 4);
    int*            psums  = (int*)carve((size_t)NB * 4);
    int*            offs   = (int*)carve((size_t)NB * 4);
    unsigned*       pkq    = (unsigned*)carve((size_t)EE * 4);

    const int* dst = edge_idx + EE;

    // fused prep (hb, Wt, xeb, be, counts=0)
    prep_misc_kernel<<<PM_TOT, 256, 0, stream>>>(
        x_flat, Wl, Wr, rel_emb, We, att, hb, Wt, xeb, be, counts);

    // CSR build (parallel scan) + pkq
    count_kernel<<<(EE + 255) / 256, 256, 0, stream>>>(dst, counts);
    psum_kernel<<<NB, 256, 0, stream>>>(counts, psums);
    pscan_kernel<<<1, 256, 0, stream>>>(psums, offs, row_ptr);
    pfin_kernel<<<NB, 256, 0, stream>>>(counts, offs, row_ptr, cursor);
    scatter_pk_kernel<<<(EE + 255) / 256, 256, 0, stream>>>(edge_idx, edge_ty, cursor, pkq);

    const float* h_cur = x_flat;
    for (int l = 0; l < LAYERS; ++l) {
        float* h_next = (l == LAYERS - 1) ? (float*)d_out : h1;
        gemm_xlxr_ab_kernel<<<(NN + 31) / 32, 256, 0, stream>>>(
            hb,
            Wt + (size_t)(l * 2 + 0) * DM * HDIM,
            Wt + (size_t)(l * 2 + 1) * DM * HDIM,
            bl + (size_t)l * HDIM, br + (size_t)l * HDIM,
            att + (size_t)l * HDIM,
            xl, xr, ab);
        node_fused_kernel<<<NN / 4, 256, 0, stream>>>(
            row_ptr, pkq, xl, xr,
            xeb + (size_t)l * NRELS * HDIM,
            ab, be + (size_t)l * NRELS * NH,
            att + (size_t)l * HDIM,
            h_cur,
            b_out + (size_t)l * DM, ln_g + (size_t)l * DM, ln_b + (size_t)l * DM,
            h_next, hb);
        h_cur = h_next;
    }
}